// Round 4
// baseline (673.460 us; speedup 1.0000x reference)
//
#include <hip/hip_runtime.h>
#include <stdint.h>

#pragma clang fp contract(off)

constexpr int B_ = 16;
constexpr int N_ = 8192;
constexpr int TPB = 1024;
constexpr int NSTEP = 10;

__device__ __forceinline__ void tf2x32(uint32_t k0, uint32_t k1,
                                       uint32_t x0, uint32_t x1,
                                       uint32_t& o0, uint32_t& o1) {
  uint32_t ks2 = k0 ^ k1 ^ 0x1BD11BDAu;
  x0 += k0; x1 += k1;
#define RND(r) { x0 += x1; x1 = (x1 << (r)) | (x1 >> (32 - (r))); x1 ^= x0; }
  RND(13) RND(15) RND(26) RND(6)   x0 += k1;  x1 += ks2 + 1u;
  RND(17) RND(29) RND(16) RND(24)  x0 += ks2; x1 += k0  + 2u;
  RND(13) RND(15) RND(26) RND(6)   x0 += k0;  x1 += k1  + 3u;
  RND(17) RND(29) RND(16) RND(24)  x0 += k1;  x1 += ks2 + 4u;
  RND(13) RND(15) RND(26) RND(6)   x0 += ks2; x1 += k0  + 5u;
#undef RND
  o0 = x0; o1 = x1;
}

__device__ __forceinline__ uint32_t rbits(uint32_t k0, uint32_t k1, uint32_t i) {
  uint32_t o0, o1;
  tf2x32(k0, k1, 0u, i, o0, o1);
  return o0 ^ o1;
}

__device__ __forceinline__ void derive_key(uint32_t j, uint32_t& k0, uint32_t& k1) {
  uint32_t o0, o1;
  tf2x32(0u, 42u, 0u, j, o0, o1);
  k0 = o0; k1 = o1;
}

__device__ __forceinline__ float u01_from_bits(uint32_t bits) {
  return __fsub_rn(__uint_as_float((bits >> 9) | 0x3f800000u), 1.0f);
}

__device__ __forceinline__ float xla_logf(float x) {
  uint32_t ix = __float_as_uint(x);
  int e = (int)((ix >> 23) & 0xffu) - 126;
  float m = __uint_as_float((ix & 0x007fffffu) | 0x3f000000u);
  float ef = (float)e;
  if (m < 0.707106781186547524f) {
    ef = __fsub_rn(ef, 1.0f);
    m = __fsub_rn(__fadd_rn(m, m), 1.0f);
  } else {
    m = __fsub_rn(m, 1.0f);
  }
  float z = __fmul_rn(m, m);
  float y = 7.0376836292e-2f;
  y = __fadd_rn(__fmul_rn(y, m), -1.1514610310e-1f);
  y = __fadd_rn(__fmul_rn(y, m),  1.1676998740e-1f);
  y = __fadd_rn(__fmul_rn(y, m), -1.2420140846e-1f);
  y = __fadd_rn(__fmul_rn(y, m),  1.4249322787e-1f);
  y = __fadd_rn(__fmul_rn(y, m), -1.6668057665e-1f);
  y = __fadd_rn(__fmul_rn(y, m),  2.0000714765e-1f);
  y = __fadd_rn(__fmul_rn(y, m), -2.4999993993e-1f);
  y = __fadd_rn(__fmul_rn(y, m),  3.3333331174e-1f);
  y = __fmul_rn(__fmul_rn(y, m), z);
  y = __fadd_rn(y, __fmul_rn(ef, -2.12194440e-4f));
  y = __fadd_rn(y, __fmul_rn(-0.5f, z));
  float r = __fadd_rn(m, y);
  r = __fadd_rn(r, __fmul_rn(ef, 0.693359375f));
  return r;
}

__device__ __forceinline__ float xla_log1p(float z) {
  if (fabsf(z) < 1e-4f)
    return __fmul_rn(__fadd_rn(__fmul_rn(-0.5f, z), 1.0f), z);
  return xla_logf(__fadd_rn(z, 1.0f));
}

__device__ __forceinline__ float erfinv_xla(float x) {
  float xx = __fmul_rn(x, x);
  float w = -xla_log1p(-xx);
  float p;
  if (w < 5.0f) {
    float ww = __fsub_rn(w, 2.5f);
    p = 2.81022636e-08f;
    p = __fadd_rn(__fmul_rn(p, ww),  3.43273939e-07f);
    p = __fadd_rn(__fmul_rn(p, ww), -3.5233877e-06f);
    p = __fadd_rn(__fmul_rn(p, ww), -4.39150654e-06f);
    p = __fadd_rn(__fmul_rn(p, ww),  0.00021858087f);
    p = __fadd_rn(__fmul_rn(p, ww), -0.00125372503f);
    p = __fadd_rn(__fmul_rn(p, ww), -0.00417768164f);
    p = __fadd_rn(__fmul_rn(p, ww),  0.246640727f);
    p = __fadd_rn(__fmul_rn(p, ww),  1.50140941f);
  } else {
    float ww = __fsub_rn(__fsqrt_rn(w), 3.0f);
    p = -0.000200214257f;
    p = __fadd_rn(__fmul_rn(p, ww),  0.000100950558f);
    p = __fadd_rn(__fmul_rn(p, ww),  0.00134934322f);
    p = __fadd_rn(__fmul_rn(p, ww), -0.00367342844f);
    p = __fadd_rn(__fmul_rn(p, ww),  0.00573950773f);
    p = __fadd_rn(__fmul_rn(p, ww), -0.0076224613f);
    p = __fadd_rn(__fmul_rn(p, ww),  0.00943887047f);
    p = __fadd_rn(__fmul_rn(p, ww),  1.00167406f);
    p = __fadd_rn(__fmul_rn(p, ww),  2.83297682f);
  }
  return __fmul_rn(p, x);
}

// ---- precompute all pick-uniforms (data-independent) + ABC normals ----
__global__ __launch_bounds__(TPB)
void rand_kernel(float* __restrict__ uni, float* __restrict__ abc) {
  const int blk = blockIdx.x;
  const int tid = threadIdx.x;
  if (blk < 640) {
    int b = blk / 40, r = blk % 40, t = r / 4, q = r % 4;
    uint32_t k0, k1;
    derive_key((uint32_t)(5 * t + 1 + q), k0, k1);
    float* dst = uni + (((size_t)b * NSTEP + t) * 4 + q) * (size_t)N_;
    float4 lo, hi;
    int n0 = 4 * tid, n1 = 4096 + 4 * tid;
    lo.x = u01_from_bits(rbits(k0, k1, (uint32_t)(b * N_ + n0 + 0)));
    lo.y = u01_from_bits(rbits(k0, k1, (uint32_t)(b * N_ + n0 + 1)));
    lo.z = u01_from_bits(rbits(k0, k1, (uint32_t)(b * N_ + n0 + 2)));
    lo.w = u01_from_bits(rbits(k0, k1, (uint32_t)(b * N_ + n0 + 3)));
    hi.x = u01_from_bits(rbits(k0, k1, (uint32_t)(b * N_ + n1 + 0)));
    hi.y = u01_from_bits(rbits(k0, k1, (uint32_t)(b * N_ + n1 + 1)));
    hi.z = u01_from_bits(rbits(k0, k1, (uint32_t)(b * N_ + n1 + 2)));
    hi.w = u01_from_bits(rbits(k0, k1, (uint32_t)(b * N_ + n1 + 3)));
    *(float4*)(dst + n0) = lo;
    *(float4*)(dst + n1) = hi;
  } else if (tid < 16) {
    const int b = tid;
    const float kLo = -0x1.fffffep-1f;
    const float kSqrt2 = 0x1.6a09e6p+0f;
    float o0 = 1.f, o1 = 1.f, o2 = 1.f;
    for (int t = 0; t < NSTEP; ++t) {
      uint32_t k0, k1;
      derive_key((uint32_t)(5 * t), k0, k1);
      float a[3];
#pragma unroll
      for (int c = 0; c < 3; ++c) {
        float f = u01_from_bits(rbits(k0, k1, (uint32_t)(b * 3 + c)));
        float u = __fadd_rn(__fmul_rn(f, 2.0f), kLo);
        u = fmaxf(kLo, u);
        a[c] = __fmul_rn(kSqrt2, erfinv_xla(u));
      }
      float na2 = __fadd_rn(__fadd_rn(__fmul_rn(a[0],a[0]),__fmul_rn(a[1],a[1])),__fmul_rn(a[2],a[2]));
      float no2 = __fadd_rn(__fadd_rn(__fmul_rn(o0,o0),__fmul_rn(o1,o1)),__fmul_rn(o2,o2));
      float nan_ = fmaxf(__fsqrt_rn(na2), 1e-12f);
      float non_ = fmaxf(__fsqrt_rn(no2), 1e-12f);
      float u0=__fdiv_rn(a[0],nan_), u1=__fdiv_rn(a[1],nan_), u2=__fdiv_rn(a[2],nan_);
      float v0=__fdiv_rn(o0,non_),  v1=__fdiv_rn(o1,non_),  v2=__fdiv_rn(o2,non_);
      float ang = __fadd_rn(__fadd_rn(__fmul_rn(u0,v0),__fmul_rn(u1,v1)),__fmul_rn(u2,v2));
      float sg = (ang > 0.f) ? 1.f : ((ang < 0.f) ? -1.f : 1.f);
      a[0]=__fmul_rn(a[0],sg); a[1]=__fmul_rn(a[1],sg); a[2]=__fmul_rn(a[2],sg);
      abc[b * 30 + t * 3 + 0] = a[0];
      abc[b * 30 + t * 3 + 1] = a[1];
      abc[b * 30 + t * 3 + 2] = a[2];
      o0 = a[0]; o1 = a[1]; o2 = a[2];
    }
  }
}

#define ACC4(v) { s = __fadd_rn(s, (v).x); s = __fadd_rn(s, (v).y); \
                  s = __fadd_rn(s, (v).z); s = __fadd_rn(s, (v).w); }

#define DSR(dst, addr, OFFSTR) \
  asm volatile("ds_read_b128 %0, %1 offset:" OFFSTR : "=v"(dst) : "v"(addr))

// Sequential (XLA-order) f32 sum of 8192 floats in LDS, inline-asm pipelined:
// triple-buffered 16-float chunks (4x ds_read_b128), 2-chunk lookahead,
// counted lgkmcnt(4) waits + sched_barrier(0) fences (rule #18).
// Dependent-add chain runs at ~4 cyc/add; LDS latency (~120cy) hidden under
// 2 stages x 64cy of adds.
__device__ float seq_sum_asm(uint32_t base) {
  float4 A0,A1,A2,A3, B0,B1,B2,B3, C0,C1,C2,C3;
  uint32_t an = base;
  DSR(A0, an, "0"); DSR(A1, an, "16"); DSR(A2, an, "32"); DSR(A3, an, "48");
  an += 64;
  DSR(B0, an, "0"); DSR(B1, an, "16"); DSR(B2, an, "32"); DSR(B3, an, "48");
  an += 64;
  float s = 0.f;
  for (int it = 0; it < 170; ++it) {      // stages 3it..3it+2, chunks 0..509
    asm volatile("s_waitcnt lgkmcnt(4)");
    __builtin_amdgcn_sched_barrier(0);
    DSR(C0, an, "0"); DSR(C1, an, "16"); DSR(C2, an, "32"); DSR(C3, an, "48");
    an += 64;
    ACC4(A0) ACC4(A1) ACC4(A2) ACC4(A3)
    asm volatile("s_waitcnt lgkmcnt(4)");
    __builtin_amdgcn_sched_barrier(0);
    DSR(A0, an, "0"); DSR(A1, an, "16"); DSR(A2, an, "32"); DSR(A3, an, "48");
    an += 64;
    ACC4(B0) ACC4(B1) ACC4(B2) ACC4(B3)
    asm volatile("s_waitcnt lgkmcnt(4)");
    __builtin_amdgcn_sched_barrier(0);
    DSR(B0, an, "0"); DSR(B1, an, "16"); DSR(B2, an, "32"); DSR(B3, an, "48");
    an += 64;
    ACC4(C0) ACC4(C1) ACC4(C2) ACC4(C3)
  }
  // epilogue: chunk 510 (A), chunk 511 (B)
  asm volatile("s_waitcnt lgkmcnt(4)");
  __builtin_amdgcn_sched_barrier(0);
  ACC4(A0) ACC4(A1) ACC4(A2) ACC4(A3)
  asm volatile("s_waitcnt lgkmcnt(0)");
  __builtin_amdgcn_sched_barrier(0);
  ACC4(B0) ACC4(B1) ACC4(B2) ACC4(B3)
  return s;
}

__global__ __launch_bounds__(TPB, 1)
void serialize_kernel(const float* __restrict__ coords, const float* __restrict__ mask,
                      const float* __restrict__ uni, const float* __restrict__ abc,
                      float* __restrict__ pts_ws, int* __restrict__ idx_ws,
                      float* __restrict__ rev_out) {
  const int b = blockIdx.x;
  const int tid = threadIdx.x;

  __shared__ __align__(16) float pm[N_ + 32];   // products / sort keys
  __shared__ float    pv[4][16];
  __shared__ int      pi[4][16];
  __shared__ float    s_abcs[NSTEP][3], s_dl[3], s_dr[3];
  __shared__ float    s_stash[48];
  __shared__ float    s_red[16];
  __shared__ float    s_mean, s_denom;

  float* pts = pts_ws + (size_t)b * N_ * 3;
  const float* cb = coords + (size_t)b * N_ * 3;
  const float* mb = mask + (size_t)b * N_;

  // ---- init: mask->regs, coords->regs+global mirror, abc->LDS ----
  if (tid < 30) s_abcs[tid / 3][tid % 3] = abc[b * 30 + tid];

  float m_[8];
  {
    float4 m4a = *(const float4*)(mb + 4 * tid);
    float4 m4b = *(const float4*)(mb + 4096 + 4 * tid);
    m_[0]=m4a.x; m_[1]=m4a.y; m_[2]=m4a.z; m_[3]=m4a.w;
    m_[4]=m4b.x; m_[5]=m4b.y; m_[6]=m4b.z; m_[7]=m4b.w;
  }

  float p_[8][3];
  {
    const float4* cA = (const float4*)(cb + 12 * tid);
    const float4* cB = (const float4*)(cb + 12288 + 12 * tid);
    float4 v0=cA[0], v1=cA[1], v2=cA[2];
    p_[0][0]=v0.x; p_[0][1]=v0.y; p_[0][2]=v0.z;
    p_[1][0]=v0.w; p_[1][1]=v1.x; p_[1][2]=v1.y;
    p_[2][0]=v1.z; p_[2][1]=v1.w; p_[2][2]=v2.x;
    p_[3][0]=v2.y; p_[3][1]=v2.z; p_[3][2]=v2.w;
    float4 w0=cB[0], w1=cB[1], w2=cB[2];
    p_[4][0]=w0.x; p_[4][1]=w0.y; p_[4][2]=w0.z;
    p_[5][0]=w0.w; p_[5][1]=w1.x; p_[5][2]=w1.y;
    p_[6][0]=w1.z; p_[6][1]=w1.w; p_[6][2]=w2.x;
    p_[7][0]=w2.y; p_[7][1]=w2.z; p_[7][2]=w2.w;
    float4* dA = (float4*)(pts + 12 * tid);
    float4* dB = (float4*)(pts + 12288 + 12 * tid);
    dA[0]=v0; dA[1]=v1; dA[2]=v2;
    dB[0]=w0; dB[1]=w1; dB[2]=w2;
  }

  // ---- denominator: mask entries are 0/1 integers -> any-order f32 sum exact
  {
    float ds = 0.f;
#pragma unroll
    for (int e = 0; e < 8; ++e) ds = __fadd_rn(ds, m_[e]);
#pragma unroll
    for (int off = 32; off > 0; off >>= 1) ds = __fadd_rn(ds, __shfl_xor(ds, off));
    if ((tid & 63) == 0) s_red[tid >> 6] = ds;
  }
  __syncthreads();
  if (tid == 0) {
    float s = 0.f;
#pragma unroll
    for (int w = 0; w < 16; ++w) s = __fadd_rn(s, s_red[w]);
    s_denom = __fadd_rn(s, 1e-9f);
  }

  float tot_[8];
#pragma unroll
  for (int e = 0; e < 8; ++e) tot_[e] = 0.f;

  __syncthreads();

  float proj_[8], sc_[8];

  for (int t = 0; t < NSTEP; ++t) {
    const float A0 = s_abcs[t][0], A1 = s_abcs[t][1], A2 = s_abcs[t][2];

    // proj (regs) + masked products into LDS for the serial mean
#pragma unroll
    for (int e = 0; e < 8; ++e)
      proj_[e] = __fadd_rn(__fadd_rn(__fmul_rn(p_[e][0], A0), __fmul_rn(p_[e][1], A1)),
                           __fmul_rn(p_[e][2], A2));
    {
      float4 w0, w1;
      w0.x=__fmul_rn(proj_[0],m_[0]); w0.y=__fmul_rn(proj_[1],m_[1]);
      w0.z=__fmul_rn(proj_[2],m_[2]); w0.w=__fmul_rn(proj_[3],m_[3]);
      w1.x=__fmul_rn(proj_[4],m_[4]); w1.y=__fmul_rn(proj_[5],m_[5]);
      w1.z=__fmul_rn(proj_[6],m_[6]); w1.w=__fmul_rn(proj_[7],m_[7]);
      ((float4*)pm)[tid] = w0;
      ((float4*)pm)[1024 + tid] = w1;
    }

    // prefetch this step's pick-uniforms (in flight across the chain)
    float4 fl[4], fh[4];
    {
      const float* ub = uni + (((size_t)b * NSTEP + t) * 4) * (size_t)N_;
#pragma unroll
      for (int q = 0; q < 4; ++q) {
        fl[q] = *(const float4*)(ub + (size_t)q * N_ + 4 * tid);
        fh[q] = *(const float4*)(ub + (size_t)q * N_ + 4096 + 4 * tid);
      }
    }
    __syncthreads();                                    // A

    // serial mean chain (tid0; regs stashed to LDS so the pipeline fits)
    if (tid == 0) {
#pragma unroll
      for (int e = 0; e < 8; ++e) {
        s_stash[e*3+0]=p_[e][0]; s_stash[e*3+1]=p_[e][1]; s_stash[e*3+2]=p_[e][2];
        s_stash[24+e]=tot_[e];
        s_stash[32+e]=proj_[e];
        s_stash[40+e]=m_[e];
      }
      __builtin_amdgcn_s_setprio(1);
      float s = seq_sum_asm((uint32_t)(uintptr_t)(pm));
      __builtin_amdgcn_s_setprio(0);
      s_mean = __fdiv_rn(s, s_denom);
#pragma unroll
      for (int e = 0; e < 8; ++e) {
        p_[e][0]=s_stash[e*3+0]; p_[e][1]=s_stash[e*3+1]; p_[e][2]=s_stash[e*3+2];
        tot_[e]=s_stash[24+e];
        proj_[e]=s_stash[32+e];
        m_[e]=s_stash[40+e];
      }
    }
    __syncthreads();                                    // B

    // score + totals + fused 4-way argmin (first-min semantics)
    const float mean = s_mean;
    const float sca = (float)(512u >> t);
    float bv[4]; int bi_[4];
#pragma unroll
    for (int q = 0; q < 4; ++q) { bv[q] = 1e30f; bi_[q] = 0x7fffffff; }
#pragma unroll
    for (int e = 0; e < 8; ++e) {
      float d = __fsub_rn(proj_[e], mean);
      float s0 = (d > 0.f) ? 1.f : ((d < 0.f) ? -1.f : 0.f);
      sc_[e] = s0;
      tot_[e] = __fadd_rn(tot_[e], __fmul_rn(s0, sca));
      float mlv = fminf(fmaxf(-s0, 0.f), m_[e]);
      float mrv = fminf(fmaxf( s0, 0.f), m_[e]);
      int n = (e < 4) ? (4*tid + e) : (4096 + 4*tid + (e - 4));
#pragma unroll
      for (int q = 0; q < 4; ++q) {
        float meff = (q < 2) ? mlv : mrv;
        float fval;
        if (e < 4) fval = (e == 0 ? fl[q].x : e == 1 ? fl[q].y : e == 2 ? fl[q].z : fl[q].w);
        else       fval = (e == 4 ? fh[q].x : e == 5 ? fh[q].y : e == 6 ? fh[q].z : fh[q].w);
        float val = __fadd_rn(fval, __fmul_rn(__fsub_rn(1.0f, meff), 1e9f));
        if (val < bv[q] || (val == bv[q] && n < bi_[q])) { bv[q] = val; bi_[q] = n; }
      }
    }
#pragma unroll
    for (int off = 32; off > 0; off >>= 1) {
#pragma unroll
      for (int q = 0; q < 4; ++q) {
        float vv = __shfl_xor(bv[q], off);
        int   ii = __shfl_xor(bi_[q], off);
        if (vv < bv[q] || (vv == bv[q] && ii < bi_[q])) { bv[q] = vv; bi_[q] = ii; }
      }
    }
    if ((tid & 63) == 0) {
      int w = tid >> 6;
#pragma unroll
      for (int q = 0; q < 4; ++q) { pv[q][w] = bv[q]; pi[q][w] = bi_[q]; }
    }
    __syncthreads();                                    // C

    if (tid < 64) {
      int w = tid & 15, q = tid >> 4;
      float v = pv[q][w]; int i = pi[q][w];
#pragma unroll
      for (int off = 1; off < 16; off <<= 1) {
        float vv = __shfl_xor(v, off);
        int   ii = __shfl_xor(i, off);
        if (vv < v || (vv == v && ii < i)) { v = vv; i = ii; }
      }
      int g0 = __shfl(i, 0), g1 = __shfl(i, 16), g2 = __shfl(i, 32), g3 = __shfl(i, 48);
      if (tid == 0) {
#pragma unroll
        for (int c = 0; c < 3; ++c) {
          s_dl[c] = __fmul_rn(__fadd_rn(pts[g0*3+c], pts[g1*3+c]), 0.5f);
          s_dr[c] = __fmul_rn(__fadd_rn(pts[g2*3+c], pts[g3*3+c]), 0.5f);
        }
      }
    }
    __syncthreads();                                    // D

    {
      float dl0=s_dl[0], dl1=s_dl[1], dl2=s_dl[2];
      float dr0=s_dr[0], dr1=s_dr[1], dr2=s_dr[2];
#pragma unroll
      for (int e = 0; e < 8; ++e) {
        float s0 = sc_[e];
        float mlv = fminf(fmaxf(-s0, 0.f), m_[e]);
        float mrv = fminf(fmaxf( s0, 0.f), m_[e]);
        p_[e][0] = __fadd_rn(__fmul_rn(__fsub_rn(p_[e][0], dl0), mlv),
                             __fmul_rn(__fsub_rn(p_[e][0], dr0), mrv));
        p_[e][1] = __fadd_rn(__fmul_rn(__fsub_rn(p_[e][1], dl1), mlv),
                             __fmul_rn(__fsub_rn(p_[e][1], dr1), mrv));
        p_[e][2] = __fadd_rn(__fmul_rn(__fsub_rn(p_[e][2], dl2), mlv),
                             __fmul_rn(__fsub_rn(p_[e][2], dr2), mrv));
      }
      float4 v0, v1, v2;
      v0.x=p_[0][0]; v0.y=p_[0][1]; v0.z=p_[0][2]; v0.w=p_[1][0];
      v1.x=p_[1][1]; v1.y=p_[1][2]; v1.z=p_[2][0]; v1.w=p_[2][1];
      v2.x=p_[2][2]; v2.y=p_[3][0]; v2.z=p_[3][1]; v2.w=p_[3][2];
      float4* dA = (float4*)(pts + 12 * tid);
      dA[0]=v0; dA[1]=v1; dA[2]=v2;
      v0.x=p_[4][0]; v0.y=p_[4][1]; v0.z=p_[4][2]; v0.w=p_[5][0];
      v1.x=p_[5][1]; v1.y=p_[5][2]; v1.z=p_[6][0]; v1.w=p_[6][1];
      v2.x=p_[6][2]; v2.y=p_[7][0]; v2.z=p_[7][1]; v2.w=p_[7][2];
      float4* dB = (float4*)(pts + 12288 + 12 * tid);
      dB[0]=v0; dB[1]=v1; dB[2]=v2;
    }
  }

  // ---- stable argsort: bitonic on (bin(total)<<13 | n), pair-indexed ----
  uint32_t* keys = reinterpret_cast<uint32_t*>(pm);
  {
    uint32_t kk_[8];
#pragma unroll
    for (int e = 0; e < 8; ++e) {
      int n = (e < 4) ? (4*tid + e) : (4096 + 4*tid + (e - 4));
      float tf = __fadd_rn(tot_[e], __fmul_rn(2048.0f, __fsub_rn(1.0f, m_[e])));
      int bin = (int)tf + 1023;
      bin = min(max(bin, 0), 4095);
      kk_[e] = ((uint32_t)bin << 13) | (uint32_t)n;
    }
    uint4 u0, u1;
    u0.x=kk_[0]; u0.y=kk_[1]; u0.z=kk_[2]; u0.w=kk_[3];
    u1.x=kk_[4]; u1.y=kk_[5]; u1.z=kk_[6]; u1.w=kk_[7];
    ((uint4*)keys)[tid] = u0;
    ((uint4*)keys)[1024 + tid] = u1;
  }
  for (uint32_t kk = 2; kk <= (uint32_t)N_; kk <<= 1) {
    for (uint32_t j = kk >> 1; j > 0; j >>= 1) {
      __syncthreads();
#pragma unroll
      for (int r = 0; r < 4; ++r) {
        int pidx = tid + (r << 10);
        int i = ((pidx & ~((int)j - 1)) << 1) | (pidx & ((int)j - 1));
        int l = i | (int)j;
        uint32_t a = keys[i], c2 = keys[l];
        bool up = ((i & (int)kk) == 0);
        if ((a > c2) == up) { keys[i] = c2; keys[l] = a; }
      }
    }
  }
  __syncthreads();
#pragma unroll
  for (int r = 0; r < 8; ++r) {
    int pos = tid + (r << 10);
    uint32_t key = keys[pos];
    int n = (int)(key & 8191u);
    idx_ws[b * N_ + pos] = n;
    rev_out[b * N_ + n] = (float)pos;
  }
}

__global__ __launch_bounds__(256)
void gather_kernel(const float* __restrict__ x, const int* __restrict__ idx_ws,
                   float* __restrict__ out) {
  int row = blockIdx.x * 4 + (threadIdx.x >> 6);
  int lane = threadIdx.x & 63;
  int b = row >> 13;
  int n = idx_ws[row];
  const float4* src = reinterpret_cast<const float4*>(x + ((size_t)(b * N_ + n)) * 256);
  float4* dst = reinterpret_cast<float4*>(out + (size_t)row * 256);
  dst[lane] = src[lane];
}

extern "C" void kernel_launch(void* const* d_in, const int* in_sizes, int n_in,
                              void* d_out, int out_size, void* d_ws, size_t ws_size,
                              hipStream_t stream) {
  const float* x      = (const float*)d_in[0];
  const float* coords = (const float*)d_in[1];
  const float* mask   = (const float*)d_in[2];
  float* out = (float*)d_out;

  float* uni    = (float*)d_ws;                               // 5,242,880 f
  float* abc    = uni + (size_t)B_ * NSTEP * 4 * N_;          // 480 f
  float* pts_ws = abc + 480;                                  // 393,216 f
  int*   idx_ws = (int*)(pts_ws + (size_t)B_ * N_ * 3);       // 131,072 i
  float* rev_out = out + (size_t)B_ * N_ * 256;

  rand_kernel<<<dim3(641), dim3(TPB), 0, stream>>>(uni, abc);
  serialize_kernel<<<dim3(B_), dim3(TPB), 0, stream>>>(coords, mask, uni, abc,
                                                       pts_ws, idx_ws, rev_out);
  gather_kernel<<<dim3(B_ * N_ / 4), dim3(256), 0, stream>>>(x, idx_ws, out);
}

// Round 7
// 599.058 us; speedup vs baseline: 1.1242x; 1.1242x over previous
//
#include <hip/hip_runtime.h>
#include <stdint.h>

#pragma clang fp contract(off)

constexpr int B_ = 16;
constexpr int N_ = 8192;
constexpr int TPB = 1024;
constexpr int NSTEP = 10;

__device__ __forceinline__ void tf2x32(uint32_t k0, uint32_t k1,
                                       uint32_t x0, uint32_t x1,
                                       uint32_t& o0, uint32_t& o1) {
  uint32_t ks2 = k0 ^ k1 ^ 0x1BD11BDAu;
  x0 += k0; x1 += k1;
#define RND(r) { x0 += x1; x1 = (x1 << (r)) | (x1 >> (32 - (r))); x1 ^= x0; }
  RND(13) RND(15) RND(26) RND(6)   x0 += k1;  x1 += ks2 + 1u;
  RND(17) RND(29) RND(16) RND(24)  x0 += ks2; x1 += k0  + 2u;
  RND(13) RND(15) RND(26) RND(6)   x0 += k0;  x1 += k1  + 3u;
  RND(17) RND(29) RND(16) RND(24)  x0 += k1;  x1 += ks2 + 4u;
  RND(13) RND(15) RND(26) RND(6)   x0 += ks2; x1 += k0  + 5u;
#undef RND
  o0 = x0; o1 = x1;
}

__device__ __forceinline__ uint32_t rbits(uint32_t k0, uint32_t k1, uint32_t i) {
  uint32_t o0, o1;
  tf2x32(k0, k1, 0u, i, o0, o1);
  return o0 ^ o1;
}

__device__ __forceinline__ void derive_key(uint32_t j, uint32_t& k0, uint32_t& k1) {
  uint32_t o0, o1;
  tf2x32(0u, 42u, 0u, j, o0, o1);
  k0 = o0; k1 = o1;
}

__device__ __forceinline__ float u01_from_bits(uint32_t bits) {
  return __fsub_rn(__uint_as_float((bits >> 9) | 0x3f800000u), 1.0f);
}

__device__ __forceinline__ float xla_logf(float x) {
  uint32_t ix = __float_as_uint(x);
  int e = (int)((ix >> 23) & 0xffu) - 126;
  float m = __uint_as_float((ix & 0x007fffffu) | 0x3f000000u);
  float ef = (float)e;
  if (m < 0.707106781186547524f) {
    ef = __fsub_rn(ef, 1.0f);
    m = __fsub_rn(__fadd_rn(m, m), 1.0f);
  } else {
    m = __fsub_rn(m, 1.0f);
  }
  float z = __fmul_rn(m, m);
  float y = 7.0376836292e-2f;
  y = __fadd_rn(__fmul_rn(y, m), -1.1514610310e-1f);
  y = __fadd_rn(__fmul_rn(y, m),  1.1676998740e-1f);
  y = __fadd_rn(__fmul_rn(y, m), -1.2420140846e-1f);
  y = __fadd_rn(__fmul_rn(y, m),  1.4249322787e-1f);
  y = __fadd_rn(__fmul_rn(y, m), -1.6668057665e-1f);
  y = __fadd_rn(__fmul_rn(y, m),  2.0000714765e-1f);
  y = __fadd_rn(__fmul_rn(y, m), -2.4999993993e-1f);
  y = __fadd_rn(__fmul_rn(y, m),  3.3333331174e-1f);
  y = __fmul_rn(__fmul_rn(y, m), z);
  y = __fadd_rn(y, __fmul_rn(ef, -2.12194440e-4f));
  y = __fadd_rn(y, __fmul_rn(-0.5f, z));
  float r = __fadd_rn(m, y);
  r = __fadd_rn(r, __fmul_rn(ef, 0.693359375f));
  return r;
}

__device__ __forceinline__ float xla_log1p(float z) {
  if (fabsf(z) < 1e-4f)
    return __fmul_rn(__fadd_rn(__fmul_rn(-0.5f, z), 1.0f), z);
  return xla_logf(__fadd_rn(z, 1.0f));
}

__device__ __forceinline__ float erfinv_xla(float x) {
  float xx = __fmul_rn(x, x);
  float w = -xla_log1p(-xx);
  float p;
  if (w < 5.0f) {
    float ww = __fsub_rn(w, 2.5f);
    p = 2.81022636e-08f;
    p = __fadd_rn(__fmul_rn(p, ww),  3.43273939e-07f);
    p = __fadd_rn(__fmul_rn(p, ww), -3.5233877e-06f);
    p = __fadd_rn(__fmul_rn(p, ww), -4.39150654e-06f);
    p = __fadd_rn(__fmul_rn(p, ww),  0.00021858087f);
    p = __fadd_rn(__fmul_rn(p, ww), -0.00125372503f);
    p = __fadd_rn(__fmul_rn(p, ww), -0.00417768164f);
    p = __fadd_rn(__fmul_rn(p, ww),  0.246640727f);
    p = __fadd_rn(__fmul_rn(p, ww),  1.50140941f);
  } else {
    float ww = __fsub_rn(__fsqrt_rn(w), 3.0f);
    p = -0.000200214257f;
    p = __fadd_rn(__fmul_rn(p, ww),  0.000100950558f);
    p = __fadd_rn(__fmul_rn(p, ww),  0.00134934322f);
    p = __fadd_rn(__fmul_rn(p, ww), -0.00367342844f);
    p = __fadd_rn(__fmul_rn(p, ww),  0.00573950773f);
    p = __fadd_rn(__fmul_rn(p, ww), -0.0076224613f);
    p = __fadd_rn(__fmul_rn(p, ww),  0.00943887047f);
    p = __fadd_rn(__fmul_rn(p, ww),  1.00167406f);
    p = __fadd_rn(__fmul_rn(p, ww),  2.83297682f);
  }
  return __fmul_rn(p, x);
}

// ---- precompute all pick-uniforms (data-independent) + ABC normals ----
__global__ __launch_bounds__(TPB)
void rand_kernel(float* __restrict__ uni, float* __restrict__ abc) {
  const int blk = blockIdx.x;
  const int tid = threadIdx.x;
  if (blk < 640) {
    int b = blk / 40, r = blk % 40, t = r / 4, q = r % 4;
    uint32_t k0, k1;
    derive_key((uint32_t)(5 * t + 1 + q), k0, k1);
    float* dst = uni + (((size_t)b * NSTEP + t) * 4 + q) * (size_t)N_;
    float4 lo, hi;
    int n0 = 4 * tid, n1 = 4096 + 4 * tid;
    lo.x = u01_from_bits(rbits(k0, k1, (uint32_t)(b * N_ + n0 + 0)));
    lo.y = u01_from_bits(rbits(k0, k1, (uint32_t)(b * N_ + n0 + 1)));
    lo.z = u01_from_bits(rbits(k0, k1, (uint32_t)(b * N_ + n0 + 2)));
    lo.w = u01_from_bits(rbits(k0, k1, (uint32_t)(b * N_ + n0 + 3)));
    hi.x = u01_from_bits(rbits(k0, k1, (uint32_t)(b * N_ + n1 + 0)));
    hi.y = u01_from_bits(rbits(k0, k1, (uint32_t)(b * N_ + n1 + 1)));
    hi.z = u01_from_bits(rbits(k0, k1, (uint32_t)(b * N_ + n1 + 2)));
    hi.w = u01_from_bits(rbits(k0, k1, (uint32_t)(b * N_ + n1 + 3)));
    *(float4*)(dst + n0) = lo;
    *(float4*)(dst + n1) = hi;
  } else if (tid < 16) {
    const int b = tid;
    const float kLo = -0x1.fffffep-1f;
    const float kSqrt2 = 0x1.6a09e6p+0f;
    float o0 = 1.f, o1 = 1.f, o2 = 1.f;
    for (int t = 0; t < NSTEP; ++t) {
      uint32_t k0, k1;
      derive_key((uint32_t)(5 * t), k0, k1);
      float a[3];
#pragma unroll
      for (int c = 0; c < 3; ++c) {
        float f = u01_from_bits(rbits(k0, k1, (uint32_t)(b * 3 + c)));
        float u = __fadd_rn(__fmul_rn(f, 2.0f), kLo);
        u = fmaxf(kLo, u);
        a[c] = __fmul_rn(kSqrt2, erfinv_xla(u));
      }
      float na2 = __fadd_rn(__fadd_rn(__fmul_rn(a[0],a[0]),__fmul_rn(a[1],a[1])),__fmul_rn(a[2],a[2]));
      float no2 = __fadd_rn(__fadd_rn(__fmul_rn(o0,o0),__fmul_rn(o1,o1)),__fmul_rn(o2,o2));
      float nan_ = fmaxf(__fsqrt_rn(na2), 1e-12f);
      float non_ = fmaxf(__fsqrt_rn(no2), 1e-12f);
      float u0=__fdiv_rn(a[0],nan_), u1=__fdiv_rn(a[1],nan_), u2=__fdiv_rn(a[2],nan_);
      float v0=__fdiv_rn(o0,non_),  v1=__fdiv_rn(o1,non_),  v2=__fdiv_rn(o2,non_);
      float ang = __fadd_rn(__fadd_rn(__fmul_rn(u0,v0),__fmul_rn(u1,v1)),__fmul_rn(u2,v2));
      float sg = (ang > 0.f) ? 1.f : ((ang < 0.f) ? -1.f : 1.f);
      a[0]=__fmul_rn(a[0],sg); a[1]=__fmul_rn(a[1],sg); a[2]=__fmul_rn(a[2],sg);
      abc[b * 30 + t * 3 + 0] = a[0];
      abc[b * 30 + t * 3 + 1] = a[1];
      abc[b * 30 + t * 3 + 2] = a[2];
      o0 = a[0]; o1 = a[1]; o2 = a[2];
    }
  }
}

// 4 dependent adds consuming one quad (accumulator pinned in v105)
#define ADDQ(a,b,c,d) \
  "v_add_f32 v105, v105, v" #a "\n\t" \
  "v_add_f32 v105, v105, v" #b "\n\t" \
  "v_add_f32 v105, v105, v" #c "\n\t" \
  "v_add_f32 v105, v105, v" #d "\n\t"

// Sequential (XLA-order) f32 sum of 8192 floats in LDS, fully pinned-register
// inline asm: buffers A=v[40:71], B=v[72:103] (32 floats each), addr v104,
// acc v105, counter s20. RA cannot spill/copy in-flight ds_read destinations
// (R5/R6 failure mode). Chunk c -> buffer c&1; per half-stage: counted
// lgkmcnt(8) wait (completes the chunk being consumed; the other 8+ newer
// reads stay in flight), 32 dependent adds interleaved quad-by-quad with the
// re-issue reads (reissue of quad k follows its 4 consuming adds in order).
// Loop 127 iters consumes chunks 0..253, issues 2..255; epilogue drains
// 254 (A) then 255 (B).
__device__ float seq_sum_asm(uint32_t base) {
  float out;
  asm volatile(
    "v_mov_b32 v104, %1\n\t"
    "v_mov_b32 v105, 0\n\t"
    // prologue: chunk0 -> A, chunk1 -> B
    "ds_read_b128 v[40:43], v104\n\t"
    "ds_read_b128 v[44:47], v104 offset:16\n\t"
    "ds_read_b128 v[48:51], v104 offset:32\n\t"
    "ds_read_b128 v[52:55], v104 offset:48\n\t"
    "ds_read_b128 v[56:59], v104 offset:64\n\t"
    "ds_read_b128 v[60:63], v104 offset:80\n\t"
    "ds_read_b128 v[64:67], v104 offset:96\n\t"
    "ds_read_b128 v[68:71], v104 offset:112\n\t"
    "v_add_u32 v104, 128, v104\n\t"
    "ds_read_b128 v[72:75], v104\n\t"
    "ds_read_b128 v[76:79], v104 offset:16\n\t"
    "ds_read_b128 v[80:83], v104 offset:32\n\t"
    "ds_read_b128 v[84:87], v104 offset:48\n\t"
    "ds_read_b128 v[88:91], v104 offset:64\n\t"
    "ds_read_b128 v[92:95], v104 offset:80\n\t"
    "ds_read_b128 v[96:99], v104 offset:96\n\t"
    "ds_read_b128 v[100:103], v104 offset:112\n\t"
    "v_add_u32 v104, 128, v104\n\t"
    "s_movk_i32 s20, 127\n\t"
    "Lchain%=:\n\t"
    // ---- A half: consume even chunk, reissue into A ----
    "s_waitcnt lgkmcnt(8)\n\t"
    ADDQ(40,41,42,43)  "ds_read_b128 v[40:43], v104\n\t"
    ADDQ(44,45,46,47)  "ds_read_b128 v[44:47], v104 offset:16\n\t"
    ADDQ(48,49,50,51)  "ds_read_b128 v[48:51], v104 offset:32\n\t"
    ADDQ(52,53,54,55)  "ds_read_b128 v[52:55], v104 offset:48\n\t"
    ADDQ(56,57,58,59)  "ds_read_b128 v[56:59], v104 offset:64\n\t"
    ADDQ(60,61,62,63)  "ds_read_b128 v[60:63], v104 offset:80\n\t"
    ADDQ(64,65,66,67)  "ds_read_b128 v[64:67], v104 offset:96\n\t"
    ADDQ(68,69,70,71)  "ds_read_b128 v[68:71], v104 offset:112\n\t"
    "v_add_u32 v104, 128, v104\n\t"
    // ---- B half: consume odd chunk, reissue into B ----
    "s_waitcnt lgkmcnt(8)\n\t"
    ADDQ(72,73,74,75)  "ds_read_b128 v[72:75], v104\n\t"
    ADDQ(76,77,78,79)  "ds_read_b128 v[76:79], v104 offset:16\n\t"
    ADDQ(80,81,82,83)  "ds_read_b128 v[80:83], v104 offset:32\n\t"
    ADDQ(84,85,86,87)  "ds_read_b128 v[84:87], v104 offset:48\n\t"
    ADDQ(88,89,90,91)  "ds_read_b128 v[88:91], v104 offset:64\n\t"
    ADDQ(92,93,94,95)  "ds_read_b128 v[92:95], v104 offset:80\n\t"
    ADDQ(96,97,98,99)  "ds_read_b128 v[96:99], v104 offset:96\n\t"
    ADDQ(100,101,102,103) "ds_read_b128 v[100:103], v104 offset:112\n\t"
    "v_add_u32 v104, 128, v104\n\t"
    "s_addk_i32 s20, -1\n\t"
    "s_cmp_lg_u32 s20, 0\n\t"
    "s_cbranch_scc1 Lchain%=\n\t"
    // ---- epilogue: chunk 254 in A, chunk 255 in B ----
    "s_waitcnt lgkmcnt(8)\n\t"
    ADDQ(40,41,42,43) ADDQ(44,45,46,47) ADDQ(48,49,50,51) ADDQ(52,53,54,55)
    ADDQ(56,57,58,59) ADDQ(60,61,62,63) ADDQ(64,65,66,67) ADDQ(68,69,70,71)
    "s_waitcnt lgkmcnt(0)\n\t"
    ADDQ(72,73,74,75) ADDQ(76,77,78,79) ADDQ(80,81,82,83) ADDQ(84,85,86,87)
    ADDQ(88,89,90,91) ADDQ(92,93,94,95) ADDQ(96,97,98,99) ADDQ(100,101,102,103)
    "v_mov_b32 %0, v105\n\t"
    : "=v"(out)
    : "v"(base)
    : "v40","v41","v42","v43","v44","v45","v46","v47",
      "v48","v49","v50","v51","v52","v53","v54","v55",
      "v56","v57","v58","v59","v60","v61","v62","v63",
      "v64","v65","v66","v67","v68","v69","v70","v71",
      "v72","v73","v74","v75","v76","v77","v78","v79",
      "v80","v81","v82","v83","v84","v85","v86","v87",
      "v88","v89","v90","v91","v92","v93","v94","v95",
      "v96","v97","v98","v99","v100","v101","v102","v103",
      "v104","v105","s20","scc","memory");
  return out;
}

__global__ __launch_bounds__(TPB, 1)
void serialize_kernel(const float* __restrict__ coords, const float* __restrict__ mask,
                      const float* __restrict__ uni, const float* __restrict__ abc,
                      float* __restrict__ pts_ws, int* __restrict__ idx_ws,
                      float* __restrict__ rev_out) {
  const int b = blockIdx.x;
  const int tid = threadIdx.x;

  __shared__ __align__(16) float pm[N_ + 32];   // products / sort keys
  __shared__ float    pv[4][16];
  __shared__ int      pi[4][16];
  __shared__ float    s_abcs[NSTEP][3], s_dl[3], s_dr[3];
  __shared__ __align__(16) float s_stash[80];
  __shared__ float    s_red[16];
  __shared__ float    s_mean, s_denom;

  float* pts = pts_ws + (size_t)b * N_ * 3;
  const float* cb = coords + (size_t)b * N_ * 3;
  const float* mb = mask + (size_t)b * N_;

  // ---- init: mask->regs, coords->regs+global mirror, abc->LDS ----
  if (tid < 30) s_abcs[tid / 3][tid % 3] = abc[b * 30 + tid];

  float m_[8];
  {
    float4 m4a = *(const float4*)(mb + 4 * tid);
    float4 m4b = *(const float4*)(mb + 4096 + 4 * tid);
    m_[0]=m4a.x; m_[1]=m4a.y; m_[2]=m4a.z; m_[3]=m4a.w;
    m_[4]=m4b.x; m_[5]=m4b.y; m_[6]=m4b.z; m_[7]=m4b.w;
  }

  float p_[8][3];
  {
    const float4* cA = (const float4*)(cb + 12 * tid);
    const float4* cB = (const float4*)(cb + 12288 + 12 * tid);
    float4 v0=cA[0], v1=cA[1], v2=cA[2];
    p_[0][0]=v0.x; p_[0][1]=v0.y; p_[0][2]=v0.z;
    p_[1][0]=v0.w; p_[1][1]=v1.x; p_[1][2]=v1.y;
    p_[2][0]=v1.z; p_[2][1]=v1.w; p_[2][2]=v2.x;
    p_[3][0]=v2.y; p_[3][1]=v2.z; p_[3][2]=v2.w;
    float4 w0=cB[0], w1=cB[1], w2=cB[2];
    p_[4][0]=w0.x; p_[4][1]=w0.y; p_[4][2]=w0.z;
    p_[5][0]=w0.w; p_[5][1]=w1.x; p_[5][2]=w1.y;
    p_[6][0]=w1.z; p_[6][1]=w1.w; p_[6][2]=w2.x;
    p_[7][0]=w2.y; p_[7][1]=w2.z; p_[7][2]=w2.w;
    float4* dA = (float4*)(pts + 12 * tid);
    float4* dB = (float4*)(pts + 12288 + 12 * tid);
    dA[0]=v0; dA[1]=v1; dA[2]=v2;
    dB[0]=w0; dB[1]=w1; dB[2]=w2;
  }

  // ---- denominator: mask entries are 0/1 integers -> any-order f32 sum exact
  {
    float ds = 0.f;
#pragma unroll
    for (int e = 0; e < 8; ++e) ds = __fadd_rn(ds, m_[e]);
#pragma unroll
    for (int off = 32; off > 0; off >>= 1) ds = __fadd_rn(ds, __shfl_xor(ds, off));
    if ((tid & 63) == 0) s_red[tid >> 6] = ds;
  }
  __syncthreads();
  if (tid == 0) {
    float s = 0.f;
#pragma unroll
    for (int w = 0; w < 16; ++w) s = __fadd_rn(s, s_red[w]);
    s_denom = __fadd_rn(s, 1e-9f);
  }

  float tot_[8];
#pragma unroll
  for (int e = 0; e < 8; ++e) tot_[e] = 0.f;

  __syncthreads();

  float proj_[8], sc_[8];

  for (int t = 0; t < NSTEP; ++t) {
    const float A0 = s_abcs[t][0], A1 = s_abcs[t][1], A2 = s_abcs[t][2];

    // proj (regs) + masked products into LDS for the serial mean
#pragma unroll
    for (int e = 0; e < 8; ++e)
      proj_[e] = __fadd_rn(__fadd_rn(__fmul_rn(p_[e][0], A0), __fmul_rn(p_[e][1], A1)),
                           __fmul_rn(p_[e][2], A2));
    {
      float4 w0, w1;
      w0.x=__fmul_rn(proj_[0],m_[0]); w0.y=__fmul_rn(proj_[1],m_[1]);
      w0.z=__fmul_rn(proj_[2],m_[2]); w0.w=__fmul_rn(proj_[3],m_[3]);
      w1.x=__fmul_rn(proj_[4],m_[4]); w1.y=__fmul_rn(proj_[5],m_[5]);
      w1.z=__fmul_rn(proj_[6],m_[6]); w1.w=__fmul_rn(proj_[7],m_[7]);
      ((float4*)pm)[tid] = w0;
      ((float4*)pm)[1024 + tid] = w1;
    }

    // prefetch this step's pick-uniforms (in flight across the chain)
    float4 fl[4], fh[4];
    {
      const float* ub = uni + (((size_t)b * NSTEP + t) * 4) * (size_t)N_;
#pragma unroll
      for (int q = 0; q < 4; ++q) {
        fl[q] = *(const float4*)(ub + (size_t)q * N_ + 4 * tid);
        fh[q] = *(const float4*)(ub + (size_t)q * N_ + 4096 + 4 * tid);
      }
    }
    __syncthreads();                                    // A

    // serial mean chain (tid0; pinned-register asm, RA-proof)
    if (tid == 0) {
#pragma unroll
      for (int e = 0; e < 8; ++e) {
        s_stash[e*3+0]=p_[e][0]; s_stash[e*3+1]=p_[e][1]; s_stash[e*3+2]=p_[e][2];
        s_stash[24+e]=tot_[e];
        s_stash[32+e]=proj_[e];
        s_stash[40+e]=m_[e];
      }
#pragma unroll
      for (int q = 0; q < 4; ++q) {
        *(float4*)&s_stash[48 + 8*q] = fl[q];
        *(float4*)&s_stash[52 + 8*q] = fh[q];
      }
      __builtin_amdgcn_s_setprio(1);
      float s = seq_sum_asm((uint32_t)(uintptr_t)(pm));
      __builtin_amdgcn_s_setprio(0);
      s_mean = __fdiv_rn(s, s_denom);
#pragma unroll
      for (int e = 0; e < 8; ++e) {
        p_[e][0]=s_stash[e*3+0]; p_[e][1]=s_stash[e*3+1]; p_[e][2]=s_stash[e*3+2];
        tot_[e]=s_stash[24+e];
        proj_[e]=s_stash[32+e];
        m_[e]=s_stash[40+e];
      }
#pragma unroll
      for (int q = 0; q < 4; ++q) {
        fl[q] = *(const float4*)&s_stash[48 + 8*q];
        fh[q] = *(const float4*)&s_stash[52 + 8*q];
      }
    }
    __syncthreads();                                    // B

    // score + totals + fused 4-way argmin (first-min semantics)
    const float mean = s_mean;
    const float sca = (float)(512u >> t);
    float bv[4]; int bi_[4];
#pragma unroll
    for (int q = 0; q < 4; ++q) { bv[q] = 1e30f; bi_[q] = 0x7fffffff; }
#pragma unroll
    for (int e = 0; e < 8; ++e) {
      float d = __fsub_rn(proj_[e], mean);
      float s0 = (d > 0.f) ? 1.f : ((d < 0.f) ? -1.f : 0.f);
      sc_[e] = s0;
      tot_[e] = __fadd_rn(tot_[e], __fmul_rn(s0, sca));
      float mlv = fminf(fmaxf(-s0, 0.f), m_[e]);
      float mrv = fminf(fmaxf( s0, 0.f), m_[e]);
      int n = (e < 4) ? (4*tid + e) : (4096 + 4*tid + (e - 4));
#pragma unroll
      for (int q = 0; q < 4; ++q) {
        float meff = (q < 2) ? mlv : mrv;
        float fval;
        if (e < 4) fval = (e == 0 ? fl[q].x : e == 1 ? fl[q].y : e == 2 ? fl[q].z : fl[q].w);
        else       fval = (e == 4 ? fh[q].x : e == 5 ? fh[q].y : e == 6 ? fh[q].z : fh[q].w);
        float val = __fadd_rn(fval, __fmul_rn(__fsub_rn(1.0f, meff), 1e9f));
        if (val < bv[q] || (val == bv[q] && n < bi_[q])) { bv[q] = val; bi_[q] = n; }
      }
    }
#pragma unroll
    for (int off = 32; off > 0; off >>= 1) {
#pragma unroll
      for (int q = 0; q < 4; ++q) {
        float vv = __shfl_xor(bv[q], off);
        int   ii = __shfl_xor(bi_[q], off);
        if (vv < bv[q] || (vv == bv[q] && ii < bi_[q])) { bv[q] = vv; bi_[q] = ii; }
      }
    }
    if ((tid & 63) == 0) {
      int w = tid >> 6;
#pragma unroll
      for (int q = 0; q < 4; ++q) { pv[q][w] = bv[q]; pi[q][w] = bi_[q]; }
    }
    __syncthreads();                                    // C

    if (tid < 64) {
      int w = tid & 15, q = tid >> 4;
      float v = pv[q][w]; int i = pi[q][w];
#pragma unroll
      for (int off = 1; off < 16; off <<= 1) {
        float vv = __shfl_xor(v, off);
        int   ii = __shfl_xor(i, off);
        if (vv < v || (vv == v && ii < i)) { v = vv; i = ii; }
      }
      int g0 = __shfl(i, 0), g1 = __shfl(i, 16), g2 = __shfl(i, 32), g3 = __shfl(i, 48);
      if (tid == 0) {
#pragma unroll
        for (int c = 0; c < 3; ++c) {
          s_dl[c] = __fmul_rn(__fadd_rn(pts[g0*3+c], pts[g1*3+c]), 0.5f);
          s_dr[c] = __fmul_rn(__fadd_rn(pts[g2*3+c], pts[g3*3+c]), 0.5f);
        }
      }
    }
    __syncthreads();                                    // D

    {
      float dl0=s_dl[0], dl1=s_dl[1], dl2=s_dl[2];
      float dr0=s_dr[0], dr1=s_dr[1], dr2=s_dr[2];
#pragma unroll
      for (int e = 0; e < 8; ++e) {
        float s0 = sc_[e];
        float mlv = fminf(fmaxf(-s0, 0.f), m_[e]);
        float mrv = fminf(fmaxf( s0, 0.f), m_[e]);
        p_[e][0] = __fadd_rn(__fmul_rn(__fsub_rn(p_[e][0], dl0), mlv),
                             __fmul_rn(__fsub_rn(p_[e][0], dr0), mrv));
        p_[e][1] = __fadd_rn(__fmul_rn(__fsub_rn(p_[e][1], dl1), mlv),
                             __fmul_rn(__fsub_rn(p_[e][1], dr1), mrv));
        p_[e][2] = __fadd_rn(__fmul_rn(__fsub_rn(p_[e][2], dl2), mlv),
                             __fmul_rn(__fsub_rn(p_[e][2], dr2), mrv));
      }
      float4 v0, v1, v2;
      v0.x=p_[0][0]; v0.y=p_[0][1]; v0.z=p_[0][2]; v0.w=p_[1][0];
      v1.x=p_[1][1]; v1.y=p_[1][2]; v1.z=p_[2][0]; v1.w=p_[2][1];
      v2.x=p_[2][2]; v2.y=p_[3][0]; v2.z=p_[3][1]; v2.w=p_[3][2];
      float4* dA = (float4*)(pts + 12 * tid);
      dA[0]=v0; dA[1]=v1; dA[2]=v2;
      v0.x=p_[4][0]; v0.y=p_[4][1]; v0.z=p_[4][2]; v0.w=p_[5][0];
      v1.x=p_[5][1]; v1.y=p_[5][2]; v1.z=p_[6][0]; v1.w=p_[6][1];
      v2.x=p_[6][2]; v2.y=p_[7][0]; v2.z=p_[7][1]; v2.w=p_[7][2];
      float4* dB = (float4*)(pts + 12288 + 12 * tid);
      dB[0]=v0; dB[1]=v1; dB[2]=v2;
    }
  }

  // ---- stable argsort: bitonic on (bin(total)<<13 | n), pair-indexed ----
  uint32_t* keys = reinterpret_cast<uint32_t*>(pm);
  {
    uint32_t kk_[8];
#pragma unroll
    for (int e = 0; e < 8; ++e) {
      int n = (e < 4) ? (4*tid + e) : (4096 + 4*tid + (e - 4));
      float tf = __fadd_rn(tot_[e], __fmul_rn(2048.0f, __fsub_rn(1.0f, m_[e])));
      int bin = (int)tf + 1023;
      bin = min(max(bin, 0), 4095);
      kk_[e] = ((uint32_t)bin << 13) | (uint32_t)n;
    }
    uint4 u0, u1;
    u0.x=kk_[0]; u0.y=kk_[1]; u0.z=kk_[2]; u0.w=kk_[3];
    u1.x=kk_[4]; u1.y=kk_[5]; u1.z=kk_[6]; u1.w=kk_[7];
    ((uint4*)keys)[tid] = u0;
    ((uint4*)keys)[1024 + tid] = u1;
  }
  for (uint32_t kk = 2; kk <= (uint32_t)N_; kk <<= 1) {
    for (uint32_t j = kk >> 1; j > 0; j >>= 1) {
      __syncthreads();
#pragma unroll
      for (int r = 0; r < 4; ++r) {
        int pidx = tid + (r << 10);
        int i = ((pidx & ~((int)j - 1)) << 1) | (pidx & ((int)j - 1));
        int l = i | (int)j;
        uint32_t a = keys[i], c2 = keys[l];
        bool up = ((i & (int)kk) == 0);
        if ((a > c2) == up) { keys[i] = c2; keys[l] = a; }
      }
    }
  }
  __syncthreads();
#pragma unroll
  for (int r = 0; r < 8; ++r) {
    int pos = tid + (r << 10);
    uint32_t key = keys[pos];
    int n = (int)(key & 8191u);
    idx_ws[b * N_ + pos] = n;
    rev_out[b * N_ + n] = (float)pos;
  }
}

__global__ __launch_bounds__(256)
void gather_kernel(const float* __restrict__ x, const int* __restrict__ idx_ws,
                   float* __restrict__ out) {
  int row = blockIdx.x * 4 + (threadIdx.x >> 6);
  int lane = threadIdx.x & 63;
  int b = row >> 13;
  int n = idx_ws[row];
  const float4* src = reinterpret_cast<const float4*>(x + ((size_t)(b * N_ + n)) * 256);
  float4* dst = reinterpret_cast<float4*>(out + (size_t)row * 256);
  dst[lane] = src[lane];
}

extern "C" void kernel_launch(void* const* d_in, const int* in_sizes, int n_in,
                              void* d_out, int out_size, void* d_ws, size_t ws_size,
                              hipStream_t stream) {
  const float* x      = (const float*)d_in[0];
  const float* coords = (const float*)d_in[1];
  const float* mask   = (const float*)d_in[2];
  float* out = (float*)d_out;

  float* uni    = (float*)d_ws;                               // 5,242,880 f
  float* abc    = uni + (size_t)B_ * NSTEP * 4 * N_;          // 480 f
  float* pts_ws = abc + 480;                                  // 393,216 f
  int*   idx_ws = (int*)(pts_ws + (size_t)B_ * N_ * 3);       // 131,072 i
  float* rev_out = out + (size_t)B_ * N_ * 256;

  rand_kernel<<<dim3(641), dim3(TPB), 0, stream>>>(uni, abc);
  serialize_kernel<<<dim3(B_), dim3(TPB), 0, stream>>>(coords, mask, uni, abc,
                                                       pts_ws, idx_ws, rev_out);
  gather_kernel<<<dim3(B_ * N_ / 4), dim3(256), 0, stream>>>(x, idx_ws, out);
}

// Round 8
// 543.662 us; speedup vs baseline: 1.2387x; 1.1019x over previous
//
#include <hip/hip_runtime.h>
#include <stdint.h>

#pragma clang fp contract(off)

constexpr int B_ = 16;
constexpr int N_ = 8192;
constexpr int TPB = 1024;
constexpr int NSTEP = 10;
constexpr int HEAT_BLOCKS = 240;
constexpr int HEAT_ITERS = 5500;   // ~146us @2.4GHz, ~440us @800MHz (<= main either way)

__device__ __forceinline__ void tf2x32(uint32_t k0, uint32_t k1,
                                       uint32_t x0, uint32_t x1,
                                       uint32_t& o0, uint32_t& o1) {
  uint32_t ks2 = k0 ^ k1 ^ 0x1BD11BDAu;
  x0 += k0; x1 += k1;
#define RND(r) { x0 += x1; x1 = (x1 << (r)) | (x1 >> (32 - (r))); x1 ^= x0; }
  RND(13) RND(15) RND(26) RND(6)   x0 += k1;  x1 += ks2 + 1u;
  RND(17) RND(29) RND(16) RND(24)  x0 += ks2; x1 += k0  + 2u;
  RND(13) RND(15) RND(26) RND(6)   x0 += k0;  x1 += k1  + 3u;
  RND(17) RND(29) RND(16) RND(24)  x0 += k1;  x1 += ks2 + 4u;
  RND(13) RND(15) RND(26) RND(6)   x0 += ks2; x1 += k0  + 5u;
#undef RND
  o0 = x0; o1 = x1;
}

__device__ __forceinline__ uint32_t rbits(uint32_t k0, uint32_t k1, uint32_t i) {
  uint32_t o0, o1;
  tf2x32(k0, k1, 0u, i, o0, o1);
  return o0 ^ o1;
}

__device__ __forceinline__ void derive_key(uint32_t j, uint32_t& k0, uint32_t& k1) {
  uint32_t o0, o1;
  tf2x32(0u, 42u, 0u, j, o0, o1);
  k0 = o0; k1 = o1;
}

__device__ __forceinline__ float u01_from_bits(uint32_t bits) {
  return __fsub_rn(__uint_as_float((bits >> 9) | 0x3f800000u), 1.0f);
}

__device__ __forceinline__ float xla_logf(float x) {
  uint32_t ix = __float_as_uint(x);
  int e = (int)((ix >> 23) & 0xffu) - 126;
  float m = __uint_as_float((ix & 0x007fffffu) | 0x3f000000u);
  float ef = (float)e;
  if (m < 0.707106781186547524f) {
    ef = __fsub_rn(ef, 1.0f);
    m = __fsub_rn(__fadd_rn(m, m), 1.0f);
  } else {
    m = __fsub_rn(m, 1.0f);
  }
  float z = __fmul_rn(m, m);
  float y = 7.0376836292e-2f;
  y = __fadd_rn(__fmul_rn(y, m), -1.1514610310e-1f);
  y = __fadd_rn(__fmul_rn(y, m),  1.1676998740e-1f);
  y = __fadd_rn(__fmul_rn(y, m), -1.2420140846e-1f);
  y = __fadd_rn(__fmul_rn(y, m),  1.4249322787e-1f);
  y = __fadd_rn(__fmul_rn(y, m), -1.6668057665e-1f);
  y = __fadd_rn(__fmul_rn(y, m),  2.0000714765e-1f);
  y = __fadd_rn(__fmul_rn(y, m), -2.4999993993e-1f);
  y = __fadd_rn(__fmul_rn(y, m),  3.3333331174e-1f);
  y = __fmul_rn(__fmul_rn(y, m), z);
  y = __fadd_rn(y, __fmul_rn(ef, -2.12194440e-4f));
  y = __fadd_rn(y, __fmul_rn(-0.5f, z));
  float r = __fadd_rn(m, y);
  r = __fadd_rn(r, __fmul_rn(ef, 0.693359375f));
  return r;
}

__device__ __forceinline__ float xla_log1p(float z) {
  if (fabsf(z) < 1e-4f)
    return __fmul_rn(__fadd_rn(__fmul_rn(-0.5f, z), 1.0f), z);
  return xla_logf(__fadd_rn(z, 1.0f));
}

__device__ __forceinline__ float erfinv_xla(float x) {
  float xx = __fmul_rn(x, x);
  float w = -xla_log1p(-xx);
  float p;
  if (w < 5.0f) {
    float ww = __fsub_rn(w, 2.5f);
    p = 2.81022636e-08f;
    p = __fadd_rn(__fmul_rn(p, ww),  3.43273939e-07f);
    p = __fadd_rn(__fmul_rn(p, ww), -3.5233877e-06f);
    p = __fadd_rn(__fmul_rn(p, ww), -4.39150654e-06f);
    p = __fadd_rn(__fmul_rn(p, ww),  0.00021858087f);
    p = __fadd_rn(__fmul_rn(p, ww), -0.00125372503f);
    p = __fadd_rn(__fmul_rn(p, ww), -0.00417768164f);
    p = __fadd_rn(__fmul_rn(p, ww),  0.246640727f);
    p = __fadd_rn(__fmul_rn(p, ww),  1.50140941f);
  } else {
    float ww = __fsub_rn(__fsqrt_rn(w), 3.0f);
    p = -0.000200214257f;
    p = __fadd_rn(__fmul_rn(p, ww),  0.000100950558f);
    p = __fadd_rn(__fmul_rn(p, ww),  0.00134934322f);
    p = __fadd_rn(__fmul_rn(p, ww), -0.00367342844f);
    p = __fadd_rn(__fmul_rn(p, ww),  0.00573950773f);
    p = __fadd_rn(__fmul_rn(p, ww), -0.0076224613f);
    p = __fadd_rn(__fmul_rn(p, ww),  0.00943887047f);
    p = __fadd_rn(__fmul_rn(p, ww),  1.00167406f);
    p = __fadd_rn(__fmul_rn(p, ww),  2.83297682f);
  }
  return __fmul_rn(p, x);
}

// ---- precompute all pick-uniforms (data-independent) + ABC normals ----
__global__ __launch_bounds__(TPB)
void rand_kernel(float* __restrict__ uni, float* __restrict__ abc) {
  const int blk = blockIdx.x;
  const int tid = threadIdx.x;
  if (blk < 640) {
    int b = blk / 40, r = blk % 40, t = r / 4, q = r % 4;
    uint32_t k0, k1;
    derive_key((uint32_t)(5 * t + 1 + q), k0, k1);
    float* dst = uni + (((size_t)b * NSTEP + t) * 4 + q) * (size_t)N_;
    float4 lo, hi;
    int n0 = 4 * tid, n1 = 4096 + 4 * tid;
    lo.x = u01_from_bits(rbits(k0, k1, (uint32_t)(b * N_ + n0 + 0)));
    lo.y = u01_from_bits(rbits(k0, k1, (uint32_t)(b * N_ + n0 + 1)));
    lo.z = u01_from_bits(rbits(k0, k1, (uint32_t)(b * N_ + n0 + 2)));
    lo.w = u01_from_bits(rbits(k0, k1, (uint32_t)(b * N_ + n0 + 3)));
    hi.x = u01_from_bits(rbits(k0, k1, (uint32_t)(b * N_ + n1 + 0)));
    hi.y = u01_from_bits(rbits(k0, k1, (uint32_t)(b * N_ + n1 + 1)));
    hi.z = u01_from_bits(rbits(k0, k1, (uint32_t)(b * N_ + n1 + 2)));
    hi.w = u01_from_bits(rbits(k0, k1, (uint32_t)(b * N_ + n1 + 3)));
    *(float4*)(dst + n0) = lo;
    *(float4*)(dst + n1) = hi;
  } else if (tid < 16) {
    const int b = tid;
    const float kLo = -0x1.fffffep-1f;
    const float kSqrt2 = 0x1.6a09e6p+0f;
    float o0 = 1.f, o1 = 1.f, o2 = 1.f;
    for (int t = 0; t < NSTEP; ++t) {
      uint32_t k0, k1;
      derive_key((uint32_t)(5 * t), k0, k1);
      float a[3];
#pragma unroll
      for (int c = 0; c < 3; ++c) {
        float f = u01_from_bits(rbits(k0, k1, (uint32_t)(b * 3 + c)));
        float u = __fadd_rn(__fmul_rn(f, 2.0f), kLo);
        u = fmaxf(kLo, u);
        a[c] = __fmul_rn(kSqrt2, erfinv_xla(u));
      }
      float na2 = __fadd_rn(__fadd_rn(__fmul_rn(a[0],a[0]),__fmul_rn(a[1],a[1])),__fmul_rn(a[2],a[2]));
      float no2 = __fadd_rn(__fadd_rn(__fmul_rn(o0,o0),__fmul_rn(o1,o1)),__fmul_rn(o2,o2));
      float nan_ = fmaxf(__fsqrt_rn(na2), 1e-12f);
      float non_ = fmaxf(__fsqrt_rn(no2), 1e-12f);
      float u0=__fdiv_rn(a[0],nan_), u1=__fdiv_rn(a[1],nan_), u2=__fdiv_rn(a[2],nan_);
      float v0=__fdiv_rn(o0,non_),  v1=__fdiv_rn(o1,non_),  v2=__fdiv_rn(o2,non_);
      float ang = __fadd_rn(__fadd_rn(__fmul_rn(u0,v0),__fmul_rn(u1,v1)),__fmul_rn(u2,v2));
      float sg = (ang > 0.f) ? 1.f : ((ang < 0.f) ? -1.f : 1.f);
      a[0]=__fmul_rn(a[0],sg); a[1]=__fmul_rn(a[1],sg); a[2]=__fmul_rn(a[2],sg);
      abc[b * 30 + t * 3 + 0] = a[0];
      abc[b * 30 + t * 3 + 1] = a[1];
      abc[b * 30 + t * 3 + 2] = a[2];
      o0 = a[0]; o1 = a[1]; o2 = a[2];
    }
  }
}

#define ACC4(v) { s = __fadd_rn(s, (v).x); s = __fadd_rn(s, (v).y); \
                  s = __fadd_rn(s, (v).z); s = __fadd_rn(s, (v).w); }

// sequential (XLA-order) f32 sum of pm[0..8191]; pm padded to 8224 floats.
// (R3 form — fastest measured variant of the serial chain.)
__device__ __forceinline__ float seq_sum_8192(const float4* v) {
  float4 a0=v[0],a1=v[1],a2=v[2],a3=v[3],a4=v[4],a5=v[5],a6=v[6],a7=v[7];
  float s = 0.f;
  for (int c = 0; c < 256; c += 2) {
    const int nb = (c + 1) << 3, na = (c + 2) << 3;
    float4 b0=v[nb+0],b1=v[nb+1],b2=v[nb+2],b3=v[nb+3];
    float4 b4=v[nb+4],b5=v[nb+5],b6=v[nb+6],b7=v[nb+7];
    ACC4(a0) ACC4(a1) ACC4(a2) ACC4(a3) ACC4(a4) ACC4(a5) ACC4(a6) ACC4(a7)
    a0=v[na+0];a1=v[na+1];a2=v[na+2];a3=v[na+3];
    a4=v[na+4];a5=v[na+5];a6=v[na+6];a7=v[na+7];   // c=254 reads pad chunk 256
    ACC4(b0) ACC4(b1) ACC4(b2) ACC4(b3) ACC4(b4) ACC4(b5) ACC4(b6) ACC4(b7)
  }
  return s;
}

__global__ __launch_bounds__(TPB, 1)
void serialize_kernel(const float* __restrict__ coords, const float* __restrict__ mask,
                      const float* __restrict__ uni, const float* __restrict__ abc,
                      float* __restrict__ pts_ws, int* __restrict__ idx_ws,
                      float* __restrict__ rev_out) {
  const int b = blockIdx.x;
  const int tid = threadIdx.x;

  // ---- heater blocks: fixed-iteration FMA burn on the other 240 CUs.
  // Raises chip utilization to ~100% so the DPM governor boosts SCLK for
  // the 16 worker blocks' latency-bound serial chains. Writes nothing;
  // deterministic; sized to finish before the workers under either clock
  // hypothesis. (Clock-hypothesis experiment, R8.)
  if (b >= B_) {
    float h0=1.0000001f, h1=1.0000002f, h2=1.0000003f, h3=1.0000004f;
    float h4=1.0000005f, h5=1.0000006f, h6=1.0000007f, h7=1.0000008f;
    const float r = 0.99999988f;
#pragma clang loop unroll_count(4)
    for (int i = 0; i < HEAT_ITERS; ++i) {
      h0 = __fmaf_rn(h0, r, 1e-30f); h1 = __fmaf_rn(h1, r, 1e-30f);
      h2 = __fmaf_rn(h2, r, 1e-30f); h3 = __fmaf_rn(h3, r, 1e-30f);
      h4 = __fmaf_rn(h4, r, 1e-30f); h5 = __fmaf_rn(h5, r, 1e-30f);
      h6 = __fmaf_rn(h6, r, 1e-30f); h7 = __fmaf_rn(h7, r, 1e-30f);
    }
    asm volatile("" :: "v"(h0),"v"(h1),"v"(h2),"v"(h3),
                       "v"(h4),"v"(h5),"v"(h6),"v"(h7));
    return;
  }

  __shared__ __align__(16) float pm[N_ + 32];   // products / sort keys
  __shared__ float    pv[4][16];
  __shared__ int      pi[4][16];
  __shared__ float    s_abcs[NSTEP][3], s_dl[3], s_dr[3];
  __shared__ __align__(16) float s_stash[80];
  __shared__ float    s_red[16];
  __shared__ float    s_mean, s_denom;

  float* pts = pts_ws + (size_t)b * N_ * 3;
  const float* cb = coords + (size_t)b * N_ * 3;
  const float* mb = mask + (size_t)b * N_;

  // ---- init: mask->regs, coords->regs+global mirror, abc->LDS ----
  if (tid < 30) s_abcs[tid / 3][tid % 3] = abc[b * 30 + tid];

  float m_[8];
  {
    float4 m4a = *(const float4*)(mb + 4 * tid);
    float4 m4b = *(const float4*)(mb + 4096 + 4 * tid);
    m_[0]=m4a.x; m_[1]=m4a.y; m_[2]=m4a.z; m_[3]=m4a.w;
    m_[4]=m4b.x; m_[5]=m4b.y; m_[6]=m4b.z; m_[7]=m4b.w;
  }

  float p_[8][3];
  {
    const float4* cA = (const float4*)(cb + 12 * tid);
    const float4* cB = (const float4*)(cb + 12288 + 12 * tid);
    float4 v0=cA[0], v1=cA[1], v2=cA[2];
    p_[0][0]=v0.x; p_[0][1]=v0.y; p_[0][2]=v0.z;
    p_[1][0]=v0.w; p_[1][1]=v1.x; p_[1][2]=v1.y;
    p_[2][0]=v1.z; p_[2][1]=v1.w; p_[2][2]=v2.x;
    p_[3][0]=v2.y; p_[3][1]=v2.z; p_[3][2]=v2.w;
    float4 w0=cB[0], w1=cB[1], w2=cB[2];
    p_[4][0]=w0.x; p_[4][1]=w0.y; p_[4][2]=w0.z;
    p_[5][0]=w0.w; p_[5][1]=w1.x; p_[5][2]=w1.y;
    p_[6][0]=w1.z; p_[6][1]=w1.w; p_[6][2]=w2.x;
    p_[7][0]=w2.y; p_[7][1]=w2.z; p_[7][2]=w2.w;
    float4* dA = (float4*)(pts + 12 * tid);
    float4* dB = (float4*)(pts + 12288 + 12 * tid);
    dA[0]=v0; dA[1]=v1; dA[2]=v2;
    dB[0]=w0; dB[1]=w1; dB[2]=w2;
  }

  // ---- denominator: mask entries are 0/1 integers -> any-order f32 sum exact
  {
    float ds = 0.f;
#pragma unroll
    for (int e = 0; e < 8; ++e) ds = __fadd_rn(ds, m_[e]);
#pragma unroll
    for (int off = 32; off > 0; off >>= 1) ds = __fadd_rn(ds, __shfl_xor(ds, off));
    if ((tid & 63) == 0) s_red[tid >> 6] = ds;
  }
  __syncthreads();
  if (tid == 0) {
    float s = 0.f;
#pragma unroll
    for (int w = 0; w < 16; ++w) s = __fadd_rn(s, s_red[w]);
    s_denom = __fadd_rn(s, 1e-9f);
  }

  float tot_[8];
#pragma unroll
  for (int e = 0; e < 8; ++e) tot_[e] = 0.f;

  __syncthreads();

  float proj_[8], sc_[8];

  for (int t = 0; t < NSTEP; ++t) {
    const float A0 = s_abcs[t][0], A1 = s_abcs[t][1], A2 = s_abcs[t][2];

    // proj (regs) + masked products into LDS for the serial mean
#pragma unroll
    for (int e = 0; e < 8; ++e)
      proj_[e] = __fadd_rn(__fadd_rn(__fmul_rn(p_[e][0], A0), __fmul_rn(p_[e][1], A1)),
                           __fmul_rn(p_[e][2], A2));
    {
      float4 w0, w1;
      w0.x=__fmul_rn(proj_[0],m_[0]); w0.y=__fmul_rn(proj_[1],m_[1]);
      w0.z=__fmul_rn(proj_[2],m_[2]); w0.w=__fmul_rn(proj_[3],m_[3]);
      w1.x=__fmul_rn(proj_[4],m_[4]); w1.y=__fmul_rn(proj_[5],m_[5]);
      w1.z=__fmul_rn(proj_[6],m_[6]); w1.w=__fmul_rn(proj_[7],m_[7]);
      ((float4*)pm)[tid] = w0;
      ((float4*)pm)[1024 + tid] = w1;
    }

    // prefetch this step's pick-uniforms (in flight across the chain)
    float4 fl[4], fh[4];
    {
      const float* ub = uni + (((size_t)b * NSTEP + t) * 4) * (size_t)N_;
#pragma unroll
      for (int q = 0; q < 4; ++q) {
        fl[q] = *(const float4*)(ub + (size_t)q * N_ + 4 * tid);
        fh[q] = *(const float4*)(ub + (size_t)q * N_ + 4096 + 4 * tid);
      }
    }
    __syncthreads();                                    // A

    // serial mean chain (tid0; regs stashed to LDS so the pipeline fits)
    if (tid == 0) {
#pragma unroll
      for (int e = 0; e < 8; ++e) {
        s_stash[e*3+0]=p_[e][0]; s_stash[e*3+1]=p_[e][1]; s_stash[e*3+2]=p_[e][2];
        s_stash[24+e]=tot_[e];
        s_stash[32+e]=proj_[e];
        s_stash[40+e]=m_[e];
      }
#pragma unroll
      for (int q = 0; q < 4; ++q) {
        *(float4*)&s_stash[48 + 8*q] = fl[q];
        *(float4*)&s_stash[52 + 8*q] = fh[q];
      }
      __builtin_amdgcn_s_setprio(1);
      float s = seq_sum_8192((const float4*)pm);
      __builtin_amdgcn_s_setprio(0);
      s_mean = __fdiv_rn(s, s_denom);
#pragma unroll
      for (int e = 0; e < 8; ++e) {
        p_[e][0]=s_stash[e*3+0]; p_[e][1]=s_stash[e*3+1]; p_[e][2]=s_stash[e*3+2];
        tot_[e]=s_stash[24+e];
        proj_[e]=s_stash[32+e];
        m_[e]=s_stash[40+e];
      }
#pragma unroll
      for (int q = 0; q < 4; ++q) {
        fl[q] = *(const float4*)&s_stash[48 + 8*q];
        fh[q] = *(const float4*)&s_stash[52 + 8*q];
      }
    }
    __syncthreads();                                    // B

    // score + totals + fused 4-way argmin (first-min semantics)
    const float mean = s_mean;
    const float sca = (float)(512u >> t);
    float bv[4]; int bi_[4];
#pragma unroll
    for (int q = 0; q < 4; ++q) { bv[q] = 1e30f; bi_[q] = 0x7fffffff; }
#pragma unroll
    for (int e = 0; e < 8; ++e) {
      float d = __fsub_rn(proj_[e], mean);
      float s0 = (d > 0.f) ? 1.f : ((d < 0.f) ? -1.f : 0.f);
      sc_[e] = s0;
      tot_[e] = __fadd_rn(tot_[e], __fmul_rn(s0, sca));
      float mlv = fminf(fmaxf(-s0, 0.f), m_[e]);
      float mrv = fminf(fmaxf( s0, 0.f), m_[e]);
      int n = (e < 4) ? (4*tid + e) : (4096 + 4*tid + (e - 4));
#pragma unroll
      for (int q = 0; q < 4; ++q) {
        float meff = (q < 2) ? mlv : mrv;
        float fval;
        if (e < 4) fval = (e == 0 ? fl[q].x : e == 1 ? fl[q].y : e == 2 ? fl[q].z : fl[q].w);
        else       fval = (e == 4 ? fh[q].x : e == 5 ? fh[q].y : e == 6 ? fh[q].z : fh[q].w);
        float val = __fadd_rn(fval, __fmul_rn(__fsub_rn(1.0f, meff), 1e9f));
        if (val < bv[q] || (val == bv[q] && n < bi_[q])) { bv[q] = val; bi_[q] = n; }
      }
    }
#pragma unroll
    for (int off = 32; off > 0; off >>= 1) {
#pragma unroll
      for (int q = 0; q < 4; ++q) {
        float vv = __shfl_xor(bv[q], off);
        int   ii = __shfl_xor(bi_[q], off);
        if (vv < bv[q] || (vv == bv[q] && ii < bi_[q])) { bv[q] = vv; bi_[q] = ii; }
      }
    }
    if ((tid & 63) == 0) {
      int w = tid >> 6;
#pragma unroll
      for (int q = 0; q < 4; ++q) { pv[q][w] = bv[q]; pi[q][w] = bi_[q]; }
    }
    __syncthreads();                                    // C

    if (tid < 64) {
      int w = tid & 15, q = tid >> 4;
      float v = pv[q][w]; int i = pi[q][w];
#pragma unroll
      for (int off = 1; off < 16; off <<= 1) {
        float vv = __shfl_xor(v, off);
        int   ii = __shfl_xor(i, off);
        if (vv < v || (vv == v && ii < i)) { v = vv; i = ii; }
      }
      int g0 = __shfl(i, 0), g1 = __shfl(i, 16), g2 = __shfl(i, 32), g3 = __shfl(i, 48);
      if (tid == 0) {
#pragma unroll
        for (int c = 0; c < 3; ++c) {
          s_dl[c] = __fmul_rn(__fadd_rn(pts[g0*3+c], pts[g1*3+c]), 0.5f);
          s_dr[c] = __fmul_rn(__fadd_rn(pts[g2*3+c], pts[g3*3+c]), 0.5f);
        }
      }
    }
    __syncthreads();                                    // D

    {
      float dl0=s_dl[0], dl1=s_dl[1], dl2=s_dl[2];
      float dr0=s_dr[0], dr1=s_dr[1], dr2=s_dr[2];
#pragma unroll
      for (int e = 0; e < 8; ++e) {
        float s0 = sc_[e];
        float mlv = fminf(fmaxf(-s0, 0.f), m_[e]);
        float mrv = fminf(fmaxf( s0, 0.f), m_[e]);
        p_[e][0] = __fadd_rn(__fmul_rn(__fsub_rn(p_[e][0], dl0), mlv),
                             __fmul_rn(__fsub_rn(p_[e][0], dr0), mrv));
        p_[e][1] = __fadd_rn(__fmul_rn(__fsub_rn(p_[e][1], dl1), mlv),
                             __fmul_rn(__fsub_rn(p_[e][1], dr1), mrv));
        p_[e][2] = __fadd_rn(__fmul_rn(__fsub_rn(p_[e][2], dl2), mlv),
                             __fmul_rn(__fsub_rn(p_[e][2], dr2), mrv));
      }
      float4 v0, v1, v2;
      v0.x=p_[0][0]; v0.y=p_[0][1]; v0.z=p_[0][2]; v0.w=p_[1][0];
      v1.x=p_[1][1]; v1.y=p_[1][2]; v1.z=p_[2][0]; v1.w=p_[2][1];
      v2.x=p_[2][2]; v2.y=p_[3][0]; v2.z=p_[3][1]; v2.w=p_[3][2];
      float4* dA = (float4*)(pts + 12 * tid);
      dA[0]=v0; dA[1]=v1; dA[2]=v2;
      v0.x=p_[4][0]; v0.y=p_[4][1]; v0.z=p_[4][2]; v0.w=p_[5][0];
      v1.x=p_[5][1]; v1.y=p_[5][2]; v1.z=p_[6][0]; v1.w=p_[6][1];
      v2.x=p_[6][2]; v2.y=p_[7][0]; v2.z=p_[7][1]; v2.w=p_[7][2];
      float4* dB = (float4*)(pts + 12288 + 12 * tid);
      dB[0]=v0; dB[1]=v1; dB[2]=v2;
    }
  }

  // ---- stable argsort: bitonic on (bin(total)<<13 | n), pair-indexed ----
  uint32_t* keys = reinterpret_cast<uint32_t*>(pm);
  {
    uint32_t kk_[8];
#pragma unroll
    for (int e = 0; e < 8; ++e) {
      int n = (e < 4) ? (4*tid + e) : (4096 + 4*tid + (e - 4));
      float tf = __fadd_rn(tot_[e], __fmul_rn(2048.0f, __fsub_rn(1.0f, m_[e])));
      int bin = (int)tf + 1023;
      bin = min(max(bin, 0), 4095);
      kk_[e] = ((uint32_t)bin << 13) | (uint32_t)n;
    }
    uint4 u0, u1;
    u0.x=kk_[0]; u0.y=kk_[1]; u0.z=kk_[2]; u0.w=kk_[3];
    u1.x=kk_[4]; u1.y=kk_[5]; u1.z=kk_[6]; u1.w=kk_[7];
    ((uint4*)keys)[tid] = u0;
    ((uint4*)keys)[1024 + tid] = u1;
  }
  for (uint32_t kk = 2; kk <= (uint32_t)N_; kk <<= 1) {
    for (uint32_t j = kk >> 1; j > 0; j >>= 1) {
      __syncthreads();
#pragma unroll
      for (int r = 0; r < 4; ++r) {
        int pidx = tid + (r << 10);
        int i = ((pidx & ~((int)j - 1)) << 1) | (pidx & ((int)j - 1));
        int l = i | (int)j;
        uint32_t a = keys[i], c2 = keys[l];
        bool up = ((i & (int)kk) == 0);
        if ((a > c2) == up) { keys[i] = c2; keys[l] = a; }
      }
    }
  }
  __syncthreads();
#pragma unroll
  for (int r = 0; r < 8; ++r) {
    int pos = tid + (r << 10);
    uint32_t key = keys[pos];
    int n = (int)(key & 8191u);
    idx_ws[b * N_ + pos] = n;
    rev_out[b * N_ + n] = (float)pos;
  }
}

__global__ __launch_bounds__(256)
void gather_kernel(const float* __restrict__ x, const int* __restrict__ idx_ws,
                   float* __restrict__ out) {
  int row = blockIdx.x * 4 + (threadIdx.x >> 6);
  int lane = threadIdx.x & 63;
  int b = row >> 13;
  int n = idx_ws[row];
  const float4* src = reinterpret_cast<const float4*>(x + ((size_t)(b * N_ + n)) * 256);
  float4* dst = reinterpret_cast<float4*>(out + (size_t)row * 256);
  dst[lane] = src[lane];
}

extern "C" void kernel_launch(void* const* d_in, const int* in_sizes, int n_in,
                              void* d_out, int out_size, void* d_ws, size_t ws_size,
                              hipStream_t stream) {
  const float* x      = (const float*)d_in[0];
  const float* coords = (const float*)d_in[1];
  const float* mask   = (const float*)d_in[2];
  float* out = (float*)d_out;

  float* uni    = (float*)d_ws;                               // 5,242,880 f
  float* abc    = uni + (size_t)B_ * NSTEP * 4 * N_;          // 480 f
  float* pts_ws = abc + 480;                                  // 393,216 f
  int*   idx_ws = (int*)(pts_ws + (size_t)B_ * N_ * 3);       // 131,072 i
  float* rev_out = out + (size_t)B_ * N_ * 256;

  rand_kernel<<<dim3(641), dim3(TPB), 0, stream>>>(uni, abc);
  serialize_kernel<<<dim3(B_ + HEAT_BLOCKS), dim3(TPB), 0, stream>>>(
      coords, mask, uni, abc, pts_ws, idx_ws, rev_out);
  gather_kernel<<<dim3(B_ * N_ / 4), dim3(256), 0, stream>>>(x, idx_ws, out);
}

// Round 10
// 539.469 us; speedup vs baseline: 1.2484x; 1.0078x over previous
//
#include <hip/hip_runtime.h>
#include <stdint.h>

#pragma clang fp contract(off)

constexpr int B_ = 16;
constexpr int N_ = 8192;
constexpr int TPB = 1024;
constexpr int NSTEP = 10;

typedef float f32x4 __attribute__((ext_vector_type(4)));

__device__ __forceinline__ void tf2x32(uint32_t k0, uint32_t k1,
                                       uint32_t x0, uint32_t x1,
                                       uint32_t& o0, uint32_t& o1) {
  uint32_t ks2 = k0 ^ k1 ^ 0x1BD11BDAu;
  x0 += k0; x1 += k1;
#define RND(r) { x0 += x1; x1 = (x1 << (r)) | (x1 >> (32 - (r))); x1 ^= x0; }
  RND(13) RND(15) RND(26) RND(6)   x0 += k1;  x1 += ks2 + 1u;
  RND(17) RND(29) RND(16) RND(24)  x0 += ks2; x1 += k0  + 2u;
  RND(13) RND(15) RND(26) RND(6)   x0 += k0;  x1 += k1  + 3u;
  RND(17) RND(29) RND(16) RND(24)  x0 += k1;  x1 += ks2 + 4u;
  RND(13) RND(15) RND(26) RND(6)   x0 += ks2; x1 += k0  + 5u;
#undef RND
  o0 = x0; o1 = x1;
}

__device__ __forceinline__ uint32_t rbits(uint32_t k0, uint32_t k1, uint32_t i) {
  uint32_t o0, o1;
  tf2x32(k0, k1, 0u, i, o0, o1);
  return o0 ^ o1;
}

__device__ __forceinline__ void derive_key(uint32_t j, uint32_t& k0, uint32_t& k1) {
  uint32_t o0, o1;
  tf2x32(0u, 42u, 0u, j, o0, o1);
  k0 = o0; k1 = o1;
}

__device__ __forceinline__ float u01_from_bits(uint32_t bits) {
  return __fsub_rn(__uint_as_float((bits >> 9) | 0x3f800000u), 1.0f);
}

__device__ __forceinline__ float xla_logf(float x) {
  uint32_t ix = __float_as_uint(x);
  int e = (int)((ix >> 23) & 0xffu) - 126;
  float m = __uint_as_float((ix & 0x007fffffu) | 0x3f000000u);
  float ef = (float)e;
  if (m < 0.707106781186547524f) {
    ef = __fsub_rn(ef, 1.0f);
    m = __fsub_rn(__fadd_rn(m, m), 1.0f);
  } else {
    m = __fsub_rn(m, 1.0f);
  }
  float z = __fmul_rn(m, m);
  float y = 7.0376836292e-2f;
  y = __fadd_rn(__fmul_rn(y, m), -1.1514610310e-1f);
  y = __fadd_rn(__fmul_rn(y, m),  1.1676998740e-1f);
  y = __fadd_rn(__fmul_rn(y, m), -1.2420140846e-1f);
  y = __fadd_rn(__fmul_rn(y, m),  1.4249322787e-1f);
  y = __fadd_rn(__fmul_rn(y, m), -1.6668057665e-1f);
  y = __fadd_rn(__fmul_rn(y, m),  2.0000714765e-1f);
  y = __fadd_rn(__fmul_rn(y, m), -2.4999993993e-1f);
  y = __fadd_rn(__fmul_rn(y, m),  3.3333331174e-1f);
  y = __fmul_rn(__fmul_rn(y, m), z);
  y = __fadd_rn(y, __fmul_rn(ef, -2.12194440e-4f));
  y = __fadd_rn(y, __fmul_rn(-0.5f, z));
  float r = __fadd_rn(m, y);
  r = __fadd_rn(r, __fmul_rn(ef, 0.693359375f));
  return r;
}

__device__ __forceinline__ float xla_log1p(float z) {
  if (fabsf(z) < 1e-4f)
    return __fmul_rn(__fadd_rn(__fmul_rn(-0.5f, z), 1.0f), z);
  return xla_logf(__fadd_rn(z, 1.0f));
}

__device__ __forceinline__ float erfinv_xla(float x) {
  float xx = __fmul_rn(x, x);
  float w = -xla_log1p(-xx);
  float p;
  if (w < 5.0f) {
    float ww = __fsub_rn(w, 2.5f);
    p = 2.81022636e-08f;
    p = __fadd_rn(__fmul_rn(p, ww),  3.43273939e-07f);
    p = __fadd_rn(__fmul_rn(p, ww), -3.5233877e-06f);
    p = __fadd_rn(__fmul_rn(p, ww), -4.39150654e-06f);
    p = __fadd_rn(__fmul_rn(p, ww),  0.00021858087f);
    p = __fadd_rn(__fmul_rn(p, ww), -0.00125372503f);
    p = __fadd_rn(__fmul_rn(p, ww), -0.00417768164f);
    p = __fadd_rn(__fmul_rn(p, ww),  0.246640727f);
    p = __fadd_rn(__fmul_rn(p, ww),  1.50140941f);
  } else {
    float ww = __fsub_rn(__fsqrt_rn(w), 3.0f);
    p = -0.000200214257f;
    p = __fadd_rn(__fmul_rn(p, ww),  0.000100950558f);
    p = __fadd_rn(__fmul_rn(p, ww),  0.00134934322f);
    p = __fadd_rn(__fmul_rn(p, ww), -0.00367342844f);
    p = __fadd_rn(__fmul_rn(p, ww),  0.00573950773f);
    p = __fadd_rn(__fmul_rn(p, ww), -0.0076224613f);
    p = __fadd_rn(__fmul_rn(p, ww),  0.00943887047f);
    p = __fadd_rn(__fmul_rn(p, ww),  1.00167406f);
    p = __fadd_rn(__fmul_rn(p, ww),  2.83297682f);
  }
  return __fmul_rn(p, x);
}

// ---- precompute pick-uniforms (steps 0..8 only; step 9's picks are dead)
// + ABC normals ----
__global__ __launch_bounds__(TPB)
void rand_kernel(float* __restrict__ uni, float* __restrict__ abc) {
  const int blk = blockIdx.x;
  const int tid = threadIdx.x;
  if (blk < 576) {               // 16 b x 9 t x 4 q
    int b = blk / 36, r = blk % 36, t = r / 4, q = r % 4;
    uint32_t k0, k1;
    derive_key((uint32_t)(5 * t + 1 + q), k0, k1);
    float* dst = uni + (((size_t)b * (NSTEP - 1) + t) * 4 + q) * (size_t)N_;
    float4 lo, hi;
    int n0 = 4 * tid, n1 = 4096 + 4 * tid;
    lo.x = u01_from_bits(rbits(k0, k1, (uint32_t)(b * N_ + n0 + 0)));
    lo.y = u01_from_bits(rbits(k0, k1, (uint32_t)(b * N_ + n0 + 1)));
    lo.z = u01_from_bits(rbits(k0, k1, (uint32_t)(b * N_ + n0 + 2)));
    lo.w = u01_from_bits(rbits(k0, k1, (uint32_t)(b * N_ + n0 + 3)));
    hi.x = u01_from_bits(rbits(k0, k1, (uint32_t)(b * N_ + n1 + 0)));
    hi.y = u01_from_bits(rbits(k0, k1, (uint32_t)(b * N_ + n1 + 1)));
    hi.z = u01_from_bits(rbits(k0, k1, (uint32_t)(b * N_ + n1 + 2)));
    hi.w = u01_from_bits(rbits(k0, k1, (uint32_t)(b * N_ + n1 + 3)));
    *(float4*)(dst + n0) = lo;
    *(float4*)(dst + n1) = hi;
  } else if (tid < 16) {
    const int b = tid;
    const float kLo = -0x1.fffffep-1f;
    const float kSqrt2 = 0x1.6a09e6p+0f;
    float o0 = 1.f, o1 = 1.f, o2 = 1.f;
    for (int t = 0; t < NSTEP; ++t) {
      uint32_t k0, k1;
      derive_key((uint32_t)(5 * t), k0, k1);
      float a[3];
#pragma unroll
      for (int c = 0; c < 3; ++c) {
        float f = u01_from_bits(rbits(k0, k1, (uint32_t)(b * 3 + c)));
        float u = __fadd_rn(__fmul_rn(f, 2.0f), kLo);
        u = fmaxf(kLo, u);
        a[c] = __fmul_rn(kSqrt2, erfinv_xla(u));
      }
      float na2 = __fadd_rn(__fadd_rn(__fmul_rn(a[0],a[0]),__fmul_rn(a[1],a[1])),__fmul_rn(a[2],a[2]));
      float no2 = __fadd_rn(__fadd_rn(__fmul_rn(o0,o0),__fmul_rn(o1,o1)),__fmul_rn(o2,o2));
      float nan_ = fmaxf(__fsqrt_rn(na2), 1e-12f);
      float non_ = fmaxf(__fsqrt_rn(no2), 1e-12f);
      float u0=__fdiv_rn(a[0],nan_), u1=__fdiv_rn(a[1],nan_), u2=__fdiv_rn(a[2],nan_);
      float v0=__fdiv_rn(o0,non_),  v1=__fdiv_rn(o1,non_),  v2=__fdiv_rn(o2,non_);
      float ang = __fadd_rn(__fadd_rn(__fmul_rn(u0,v0),__fmul_rn(u1,v1)),__fmul_rn(u2,v2));
      float sg = (ang > 0.f) ? 1.f : ((ang < 0.f) ? -1.f : 1.f);
      a[0]=__fmul_rn(a[0],sg); a[1]=__fmul_rn(a[1],sg); a[2]=__fmul_rn(a[2],sg);
      abc[b * 30 + t * 3 + 0] = a[0];
      abc[b * 30 + t * 3 + 1] = a[1];
      abc[b * 30 + t * 3 + 2] = a[2];
      o0 = a[0]; o1 = a[1]; o2 = a[2];
    }
  }
}

#define ACC4(v) { s = __fadd_rn(s, (v).x); s = __fadd_rn(s, (v).y); \
                  s = __fadd_rn(s, (v).z); s = __fadd_rn(s, (v).w); }

// sequential (XLA-order) f32 sum of pm[0..8191]; pm padded to 8224 floats.
// (R3 form — fastest measured; 13 cyc/dep-add is the lone-wave HW floor,
// confirmed by the R8 heater experiment.)
__device__ __forceinline__ float seq_sum_8192(const float4* v) {
  float4 a0=v[0],a1=v[1],a2=v[2],a3=v[3],a4=v[4],a5=v[5],a6=v[6],a7=v[7];
  float s = 0.f;
  for (int c = 0; c < 256; c += 2) {
    const int nb = (c + 1) << 3, na = (c + 2) << 3;
    float4 b0=v[nb+0],b1=v[nb+1],b2=v[nb+2],b3=v[nb+3];
    float4 b4=v[nb+4],b5=v[nb+5],b6=v[nb+6],b7=v[nb+7];
    ACC4(a0) ACC4(a1) ACC4(a2) ACC4(a3) ACC4(a4) ACC4(a5) ACC4(a6) ACC4(a7)
    a0=v[na+0];a1=v[na+1];a2=v[na+2];a3=v[na+3];
    a4=v[na+4];a5=v[na+5];a6=v[na+6];a7=v[na+7];   // c=254 reads pad chunk 256
    ACC4(b0) ACC4(b1) ACC4(b2) ACC4(b3) ACC4(b4) ACC4(b5) ACC4(b6) ACC4(b7)
  }
  return s;
}

__global__ __launch_bounds__(TPB, 1)
void serialize_kernel(const float* __restrict__ coords, const float* __restrict__ mask,
                      const float* __restrict__ uni, const float* __restrict__ abc,
                      float* __restrict__ pts_ws, int* __restrict__ idx_ws,
                      float* __restrict__ rev_out) {
  const int b = blockIdx.x;
  const int tid = threadIdx.x;

  __shared__ __align__(16) float pm[N_ + 32];   // products / sort keys
  __shared__ float    pv[4][16];
  __shared__ int      pi[4][16];
  __shared__ float    s_abcs[NSTEP][3], s_dl[3], s_dr[3];
  __shared__ __align__(16) float s_stash[80];
  __shared__ float    s_red[16];
  __shared__ float    s_mean, s_denom;

  float* pts = pts_ws + (size_t)b * N_ * 3;
  const float* cb = coords + (size_t)b * N_ * 3;
  const float* mb = mask + (size_t)b * N_;

  // ---- init: mask->regs, coords->regs+global mirror, abc->LDS ----
  if (tid < 30) s_abcs[tid / 3][tid % 3] = abc[b * 30 + tid];

  float m_[8];
  {
    float4 m4a = *(const float4*)(mb + 4 * tid);
    float4 m4b = *(const float4*)(mb + 4096 + 4 * tid);
    m_[0]=m4a.x; m_[1]=m4a.y; m_[2]=m4a.z; m_[3]=m4a.w;
    m_[4]=m4b.x; m_[5]=m4b.y; m_[6]=m4b.z; m_[7]=m4b.w;
  }

  float p_[8][3];
  {
    const float4* cA = (const float4*)(cb + 12 * tid);
    const float4* cB = (const float4*)(cb + 12288 + 12 * tid);
    float4 v0=cA[0], v1=cA[1], v2=cA[2];
    p_[0][0]=v0.x; p_[0][1]=v0.y; p_[0][2]=v0.z;
    p_[1][0]=v0.w; p_[1][1]=v1.x; p_[1][2]=v1.y;
    p_[2][0]=v1.z; p_[2][1]=v1.w; p_[2][2]=v2.x;
    p_[3][0]=v2.y; p_[3][1]=v2.z; p_[3][2]=v2.w;
    float4 w0=cB[0], w1=cB[1], w2=cB[2];
    p_[4][0]=w0.x; p_[4][1]=w0.y; p_[4][2]=w0.z;
    p_[5][0]=w0.w; p_[5][1]=w1.x; p_[5][2]=w1.y;
    p_[6][0]=w1.z; p_[6][1]=w1.w; p_[6][2]=w2.x;
    p_[7][0]=w2.y; p_[7][1]=w2.z; p_[7][2]=w2.w;
    float4* dA = (float4*)(pts + 12 * tid);
    float4* dB = (float4*)(pts + 12288 + 12 * tid);
    dA[0]=v0; dA[1]=v1; dA[2]=v2;
    dB[0]=w0; dB[1]=w1; dB[2]=w2;
  }

  // ---- denominator: mask entries are 0/1 integers -> any-order f32 sum exact
  {
    float ds = 0.f;
#pragma unroll
    for (int e = 0; e < 8; ++e) ds = __fadd_rn(ds, m_[e]);
#pragma unroll
    for (int off = 32; off > 0; off >>= 1) ds = __fadd_rn(ds, __shfl_xor(ds, off));
    if ((tid & 63) == 0) s_red[tid >> 6] = ds;
  }
  __syncthreads();
  if (tid == 0) {
    float s = 0.f;
#pragma unroll
    for (int w = 0; w < 16; ++w) s = __fadd_rn(s, s_red[w]);
    s_denom = __fadd_rn(s, 1e-9f);
  }

  float tot_[8];
#pragma unroll
  for (int e = 0; e < 8; ++e) tot_[e] = 0.f;

  __syncthreads();

  float proj_[8], sc_[8];

  for (int t = 0; t < NSTEP; ++t) {
    const bool live = (t < NSTEP - 1);     // block-uniform; t=9 picks/update are dead
    const float A0 = s_abcs[t][0], A1 = s_abcs[t][1], A2 = s_abcs[t][2];

    // proj (regs) + masked products into LDS for the serial mean
#pragma unroll
    for (int e = 0; e < 8; ++e)
      proj_[e] = __fadd_rn(__fadd_rn(__fmul_rn(p_[e][0], A0), __fmul_rn(p_[e][1], A1)),
                           __fmul_rn(p_[e][2], A2));
    {
      float4 w0, w1;
      w0.x=__fmul_rn(proj_[0],m_[0]); w0.y=__fmul_rn(proj_[1],m_[1]);
      w0.z=__fmul_rn(proj_[2],m_[2]); w0.w=__fmul_rn(proj_[3],m_[3]);
      w1.x=__fmul_rn(proj_[4],m_[4]); w1.y=__fmul_rn(proj_[5],m_[5]);
      w1.z=__fmul_rn(proj_[6],m_[6]); w1.w=__fmul_rn(proj_[7],m_[7]);
      ((float4*)pm)[tid] = w0;
      ((float4*)pm)[1024 + tid] = w1;
    }

    // prefetch this step's pick-uniforms (in flight across the chain)
    float4 fl[4], fh[4];
    if (live) {
      const float* ub = uni + (((size_t)b * (NSTEP - 1) + t) * 4) * (size_t)N_;
#pragma unroll
      for (int q = 0; q < 4; ++q) {
        fl[q] = *(const float4*)(ub + (size_t)q * N_ + 4 * tid);
        fh[q] = *(const float4*)(ub + (size_t)q * N_ + 4096 + 4 * tid);
      }
    }
    __syncthreads();                                    // A

    // serial mean chain (tid0; regs stashed to LDS so the pipeline fits)
    if (tid == 0) {
#pragma unroll
      for (int e = 0; e < 8; ++e) {
        s_stash[e*3+0]=p_[e][0]; s_stash[e*3+1]=p_[e][1]; s_stash[e*3+2]=p_[e][2];
        s_stash[24+e]=tot_[e];
        s_stash[32+e]=proj_[e];
        s_stash[40+e]=m_[e];
      }
      if (live) {
#pragma unroll
        for (int q = 0; q < 4; ++q) {
          *(float4*)&s_stash[48 + 8*q] = fl[q];
          *(float4*)&s_stash[52 + 8*q] = fh[q];
        }
      }
      __builtin_amdgcn_s_setprio(1);
      float s = seq_sum_8192((const float4*)pm);
      __builtin_amdgcn_s_setprio(0);
      s_mean = __fdiv_rn(s, s_denom);
#pragma unroll
      for (int e = 0; e < 8; ++e) {
        p_[e][0]=s_stash[e*3+0]; p_[e][1]=s_stash[e*3+1]; p_[e][2]=s_stash[e*3+2];
        tot_[e]=s_stash[24+e];
        proj_[e]=s_stash[32+e];
        m_[e]=s_stash[40+e];
      }
      if (live) {
#pragma unroll
        for (int q = 0; q < 4; ++q) {
          fl[q] = *(const float4*)&s_stash[48 + 8*q];
          fh[q] = *(const float4*)&s_stash[52 + 8*q];
        }
      }
    }
    __syncthreads();                                    // B

    // score + totals (always) + fused 4-way argmin (live steps only)
    const float mean = s_mean;
    const float sca = (float)(512u >> t);
    float bv[4]; int bi_[4];
#pragma unroll
    for (int q = 0; q < 4; ++q) { bv[q] = 1e30f; bi_[q] = 0x7fffffff; }
#pragma unroll
    for (int e = 0; e < 8; ++e) {
      float d = __fsub_rn(proj_[e], mean);
      float s0 = (d > 0.f) ? 1.f : ((d < 0.f) ? -1.f : 0.f);
      sc_[e] = s0;
      tot_[e] = __fadd_rn(tot_[e], __fmul_rn(s0, sca));
      if (live) {
        float mlv = fminf(fmaxf(-s0, 0.f), m_[e]);
        float mrv = fminf(fmaxf( s0, 0.f), m_[e]);
        int n = (e < 4) ? (4*tid + e) : (4096 + 4*tid + (e - 4));
#pragma unroll
        for (int q = 0; q < 4; ++q) {
          float meff = (q < 2) ? mlv : mrv;
          float fval;
          if (e < 4) fval = (e == 0 ? fl[q].x : e == 1 ? fl[q].y : e == 2 ? fl[q].z : fl[q].w);
          else       fval = (e == 4 ? fh[q].x : e == 5 ? fh[q].y : e == 6 ? fh[q].z : fh[q].w);
          float val = __fadd_rn(fval, __fmul_rn(__fsub_rn(1.0f, meff), 1e9f));
          if (val < bv[q] || (val == bv[q] && n < bi_[q])) { bv[q] = val; bi_[q] = n; }
        }
      }
    }
    if (!live) break;                       // t=9: picks/duplets/update are dead

#pragma unroll
    for (int off = 32; off > 0; off >>= 1) {
#pragma unroll
      for (int q = 0; q < 4; ++q) {
        float vv = __shfl_xor(bv[q], off);
        int   ii = __shfl_xor(bi_[q], off);
        if (vv < bv[q] || (vv == bv[q] && ii < bi_[q])) { bv[q] = vv; bi_[q] = ii; }
      }
    }
    if ((tid & 63) == 0) {
      int w = tid >> 6;
#pragma unroll
      for (int q = 0; q < 4; ++q) { pv[q][w] = bv[q]; pi[q][w] = bi_[q]; }
    }
    __syncthreads();                                    // C

    if (tid < 64) {
      int w = tid & 15, q = tid >> 4;
      float v = pv[q][w]; int i = pi[q][w];
#pragma unroll
      for (int off = 1; off < 16; off <<= 1) {
        float vv = __shfl_xor(v, off);
        int   ii = __shfl_xor(i, off);
        if (vv < v || (vv == v && ii < i)) { v = vv; i = ii; }
      }
      int g0 = __shfl(i, 0), g1 = __shfl(i, 16), g2 = __shfl(i, 32), g3 = __shfl(i, 48);
      if (tid == 0) {
#pragma unroll
        for (int c = 0; c < 3; ++c) {
          s_dl[c] = __fmul_rn(__fadd_rn(pts[g0*3+c], pts[g1*3+c]), 0.5f);
          s_dr[c] = __fmul_rn(__fadd_rn(pts[g2*3+c], pts[g3*3+c]), 0.5f);
        }
      }
    }
    __syncthreads();                                    // D

    {
      float dl0=s_dl[0], dl1=s_dl[1], dl2=s_dl[2];
      float dr0=s_dr[0], dr1=s_dr[1], dr2=s_dr[2];
#pragma unroll
      for (int e = 0; e < 8; ++e) {
        float s0 = sc_[e];
        float mlv = fminf(fmaxf(-s0, 0.f), m_[e]);
        float mrv = fminf(fmaxf( s0, 0.f), m_[e]);
        p_[e][0] = __fadd_rn(__fmul_rn(__fsub_rn(p_[e][0], dl0), mlv),
                             __fmul_rn(__fsub_rn(p_[e][0], dr0), mrv));
        p_[e][1] = __fadd_rn(__fmul_rn(__fsub_rn(p_[e][1], dl1), mlv),
                             __fmul_rn(__fsub_rn(p_[e][1], dr1), mrv));
        p_[e][2] = __fadd_rn(__fmul_rn(__fsub_rn(p_[e][2], dl2), mlv),
                             __fmul_rn(__fsub_rn(p_[e][2], dr2), mrv));
      }
      float4 v0, v1, v2;
      v0.x=p_[0][0]; v0.y=p_[0][1]; v0.z=p_[0][2]; v0.w=p_[1][0];
      v1.x=p_[1][1]; v1.y=p_[1][2]; v1.z=p_[2][0]; v1.w=p_[2][1];
      v2.x=p_[2][2]; v2.y=p_[3][0]; v2.z=p_[3][1]; v2.w=p_[3][2];
      float4* dA = (float4*)(pts + 12 * tid);
      dA[0]=v0; dA[1]=v1; dA[2]=v2;
      v0.x=p_[4][0]; v0.y=p_[4][1]; v0.z=p_[4][2]; v0.w=p_[5][0];
      v1.x=p_[5][1]; v1.y=p_[5][2]; v1.z=p_[6][0]; v1.w=p_[6][1];
      v2.x=p_[6][2]; v2.y=p_[7][0]; v2.z=p_[7][1]; v2.w=p_[7][2];
      float4* dB = (float4*)(pts + 12288 + 12 * tid);
      dB[0]=v0; dB[1]=v1; dB[2]=v2;
    }
  }

  // ---- stable argsort: bitonic on (bin(total)<<13 | n), pair-indexed ----
  uint32_t* keys = reinterpret_cast<uint32_t*>(pm);
  {
    uint32_t kk_[8];
#pragma unroll
    for (int e = 0; e < 8; ++e) {
      int n = (e < 4) ? (4*tid + e) : (4096 + 4*tid + (e - 4));
      float tf = __fadd_rn(tot_[e], __fmul_rn(2048.0f, __fsub_rn(1.0f, m_[e])));
      int bin = (int)tf + 1023;
      bin = min(max(bin, 0), 4095);
      kk_[e] = ((uint32_t)bin << 13) | (uint32_t)n;
    }
    uint4 u0, u1;
    u0.x=kk_[0]; u0.y=kk_[1]; u0.z=kk_[2]; u0.w=kk_[3];
    u1.x=kk_[4]; u1.y=kk_[5]; u1.z=kk_[6]; u1.w=kk_[7];
    ((uint4*)keys)[tid] = u0;
    ((uint4*)keys)[1024 + tid] = u1;
  }
  for (uint32_t kk = 2; kk <= (uint32_t)N_; kk <<= 1) {
    for (uint32_t j = kk >> 1; j > 0; j >>= 1) {
      __syncthreads();
#pragma unroll
      for (int r = 0; r < 4; ++r) {
        int pidx = tid + (r << 10);
        int i = ((pidx & ~((int)j - 1)) << 1) | (pidx & ((int)j - 1));
        int l = i | (int)j;
        uint32_t a = keys[i], c2 = keys[l];
        bool up = ((i & (int)kk) == 0);
        if ((a > c2) == up) { keys[i] = c2; keys[l] = a; }
      }
    }
  }
  __syncthreads();
#pragma unroll
  for (int r = 0; r < 8; ++r) {
    int pos = tid + (r << 10);
    uint32_t key = keys[pos];
    int n = (int)(key & 8191u);
    idx_ws[b * N_ + pos] = n;
    rev_out[b * N_ + n] = (float)pos;
  }
}

__global__ __launch_bounds__(512)
void gather_kernel(const float* __restrict__ x, const int* __restrict__ idx_ws,
                   float* __restrict__ out) {
  int row = blockIdx.x * 8 + (threadIdx.x >> 6);
  int lane = threadIdx.x & 63;
  int b = row >> 13;
  int n = idx_ws[row];
  const f32x4* src = reinterpret_cast<const f32x4*>(x + ((size_t)(b * N_ + n)) * 256);
  f32x4* dst = reinterpret_cast<f32x4*>(out + (size_t)row * 256);
  f32x4 v = __builtin_nontemporal_load(&src[lane]);
  __builtin_nontemporal_store(v, &dst[lane]);
}

extern "C" void kernel_launch(void* const* d_in, const int* in_sizes, int n_in,
                              void* d_out, int out_size, void* d_ws, size_t ws_size,
                              hipStream_t stream) {
  const float* x      = (const float*)d_in[0];
  const float* coords = (const float*)d_in[1];
  const float* mask   = (const float*)d_in[2];
  float* out = (float*)d_out;

  float* uni    = (float*)d_ws;                               // 16*9*4*8192 f
  float* abc    = uni + (size_t)B_ * (NSTEP - 1) * 4 * N_;    // 480 f
  float* pts_ws = abc + 480;                                  // 393,216 f
  int*   idx_ws = (int*)(pts_ws + (size_t)B_ * N_ * 3);       // 131,072 i
  float* rev_out = out + (size_t)B_ * N_ * 256;

  rand_kernel<<<dim3(577), dim3(TPB), 0, stream>>>(uni, abc);
  serialize_kernel<<<dim3(B_), dim3(TPB), 0, stream>>>(coords, mask, uni, abc,
                                                       pts_ws, idx_ws, rev_out);
  gather_kernel<<<dim3(B_ * N_ / 8), dim3(512), 0, stream>>>(x, idx_ws, out);
}